// Round 10
// baseline (204.109 us; speedup 1.0000x reference)
//
#include <hip/hip_runtime.h>
#include <math.h>

// Problem constants (fixed by the reference setup_inputs()).
#define TT 3
#define NN 50000
#define DD 64
#define EE 800000
#define LL 2
#define NK3 (NN * TT)              // 150000 (row,tau) CSR keys
#define NB3 ((NK3 + 255) / 256)    // 586 scan blocks
#define CH 96                      // edge-walk LDS chunk (>= typical node degree)
#define NBC ((EE + 255) / 256)     // 3125 count blocks
#define NBM ((NN + 63) / 64)       // 782 mm0 blocks

typedef _Float16 h4 __attribute__((ext_vector_type(4)));
typedef float f4 __attribute__((ext_vector_type(4)));

// ---------------------------------------------------------------------------
// k_fusedA: three INDEPENDENT jobs partitioned by blockIdx:
//   [0, NBC)          edge count + keyrank  (atomic rank capture)
//   [NBC, NBC+NBM)    layer-0 GEMM (Bt built from f32 we0/thj0 directly)
//   NBC+NBM           k_small: rg/sig for both layers + f16 B tables
// ---------------------------------------------------------------------------
__global__ __launch_bounds__(256) void k_fusedA(
    const int* __restrict__ row, const int* __restrict__ et,
    int* __restrict__ counts, unsigned* __restrict__ keyrank,
    const float* __restrict__ x,
    const float* __restrict__ we,    // [L,64,64]
    const float* __restrict__ thj,   // [L,3,64]
    _Float16* __restrict__ hw0,      // [N,64]
    float* __restrict__ ahj0,        // [N,4]
    const float* __restrict__ ef0,
    const float* __restrict__ tg,    // [L,T,D]
    const float* __restrict__ wr,    // [L,D,D]
    float* __restrict__ rg,          // [L*9]
    float* __restrict__ sig,         // [L*192]
    _Float16* __restrict__ bf)       // [L*80*64] Bt[c][k] f16
{
    __shared__ _Float16 Ah[64][68];
    __shared__ _Float16 Bt[80][68];
    int b = blockIdx.x, tid = threadIdx.x;

    if (b < NBC) {
        // ---- edge count + rank ----
        int e = b * 256 + tid;
        if (e < EE) {
            int key = row[e] * 3 + et[e];
            int r = atomicAdd(&counts[key], 1);
            keyrank[e] = ((unsigned)key << 14) | (unsigned)r;  // rank << 16384
        }
        return;
    }
    if (b < NBC + NBM) {
        // ---- layer-0 GEMM: C[N,80] = x @ [we0 | thj0 | 0] ----
        long rbase = (long)(b - NBC) * 64;
        #pragma unroll
        for (int it = 0; it < 4; ++it) {
            int flat = (tid + it * 256) * 4;
            int r = flat >> 6, k = flat & 63;
            h4 hv = {};
            if (rbase + r < NN) {
                float4 v = *(const float4*)&x[(rbase + r) * 64 + k];
                hv = h4{ (_Float16)v.x, (_Float16)v.y, (_Float16)v.z, (_Float16)v.w };
            }
            *(h4*)&Ah[r][k] = hv;
        }
        for (int idx = tid; idx < 80 * 64; idx += 256) {
            int c = idx >> 6, k = idx & 63;
            float v = 0.f;
            if (c < 64) v = we[k * 64 + c];
            else if (c < 67) v = thj[(c - 64) * 64 + k];
            Bt[c][k] = (_Float16)v;
        }
        __syncthreads();
        int wid = tid >> 6, lane = tid & 63;
        int r16 = lane & 15, kq = lane >> 4;
        f4 acc[5] = {};
        #pragma unroll
        for (int ks = 0; ks < 4; ++ks) {
            int k0 = ks * 16 + kq * 4;
            h4 a = *(h4*)&Ah[wid * 16 + r16][k0];
            #pragma unroll
            for (int ct = 0; ct < 5; ++ct) {
                h4 bb = *(h4*)&Bt[ct * 16 + r16][k0];
                acc[ct] = __builtin_amdgcn_mfma_f32_16x16x16f16(a, bb, acc[ct], 0, 0, 0);
            }
        }
        #pragma unroll
        for (int j = 0; j < 4; ++j) {
            long g = rbase + wid * 16 + kq * 4 + j;
            if (g < NN) {
                #pragma unroll
                for (int ct = 0; ct < 4; ++ct)
                    hw0[g * 64 + ct * 16 + r16] = (_Float16)acc[ct][j];
                if (r16 < 3) ahj0[g * 4 + r16] = acc[4][j];
            }
        }
        return;
    }
    // ---- k_small (1 block): rg/sig both layers + f16 B tables ----
    float* ef_l = (float*)&Ah[0][0];        // 192 floats, aliased into Ah
    float* efn  = ef_l + TT * DD;           // 192 floats
    for (int l = 0; l < LL; ++l)
        for (int idx = tid; idx < 80 * 64; idx += 256) {
            int c = idx >> 6, k = idx & 63;
            float v = 0.f;
            if (c < 64) v = we[l * 4096 + k * 64 + c];
            else if (c < 67) v = thj[l * 192 + (c - 64) * 64 + k];
            bf[l * 5120 + idx] = (_Float16)v;
        }
    if (tid < TT * DD) ef_l[tid] = ef0[tid];
    __syncthreads();
    for (int layer = 0; layer < LL; ++layer) {
        if (tid < TT * TT) {
            int t = tid / TT, tau = tid % TT;
            float s = 0.f;
            #pragma unroll
            for (int k = 0; k < DD; ++k)
                s += ef_l[tau * DD + k] * tg[layer * TT * DD + t * DD + k];
            rg[layer * TT * TT + tid] = s;
        }
        if (tid < TT * DD) {
            int tau = tid / DD, d = tid % DD;
            float s = 0.f;
            #pragma unroll
            for (int k = 0; k < DD; ++k)
                s += ef_l[tau * DD + k] * wr[layer * DD * DD + k * DD + d];
            efn[tid] = s;
            sig[layer * TT * DD + tid] = 1.f / (1.f + expf(-s));
        }
        __syncthreads();
        if (tid < TT * DD) ef_l[tid] = fmaxf(efn[tid], 0.f);
        __syncthreads();
    }
}

// ---------------------------------------------------------------------------
// CSR scan + emit + atomic-free scatter (unchanged from R9).
// ---------------------------------------------------------------------------
__global__ void k_bsum(const int* __restrict__ counts, int* __restrict__ bsum)
{
    __shared__ int red[256];
    int i = blockIdx.x * 256 + threadIdx.x;
    red[threadIdx.x] = (i < NK3) ? counts[i] : 0;
    __syncthreads();
    for (int off = 128; off >= 1; off >>= 1) {
        if (threadIdx.x < off) red[threadIdx.x] += red[threadIdx.x + off];
        __syncthreads();
    }
    if (threadIdx.x == 0) bsum[blockIdx.x] = red[0];
}

__global__ void k_emit2(const int* __restrict__ counts,
                        const int* __restrict__ bsum,
                        int* __restrict__ csroff)
{
    __shared__ int s[256];
    __shared__ int bpre_s;
    int b = blockIdx.x, tid = threadIdx.x;
    int pp = 0;
    for (int i = tid; i < b; i += 256) pp += bsum[i];
    s[tid] = pp;
    __syncthreads();
    for (int off = 128; off >= 1; off >>= 1) {
        if (tid < off) s[tid] += s[tid + off];
        __syncthreads();
    }
    if (tid == 0) bpre_s = s[0];
    __syncthreads();
    int bpre = bpre_s;
    int idx = b * 256 + tid;
    int c = (idx < NK3) ? counts[idx] : 0;
    s[tid] = c;
    __syncthreads();
    for (int off = 1; off < 256; off <<= 1) {
        int u = (tid >= off) ? s[tid - off] : 0;
        __syncthreads();
        s[tid] += u;
        __syncthreads();
    }
    if (idx < NK3) csroff[idx] = bpre + s[tid] - c;
    if (b == NB3 - 1 && tid == 255) csroff[NK3] = bpre + s[255];
}

__global__ void k_scatter3r(const unsigned* __restrict__ keyrank,
                            const int* __restrict__ col,
                            const int* __restrict__ csroff,
                            unsigned short* __restrict__ pk)
{
    int e = blockIdx.x * 256 + threadIdx.x;
    if (e < EE) {
        unsigned kr = keyrank[e];
        int pos = csroff[kr >> 14] + (int)(kr & 16383u);
        pk[pos] = (unsigned short)col[e];   // col < 50000 < 2^16
    }
}

// ---------------------------------------------------------------------------
// k_edge0mm: layer-0 aggregation FUSED with the layer-1 GEMM. One node per
// wave (4 waves/block). Wave computes o0..o2 (flat walk, unroll x4), forms
// h1 rows = x + relu(o) in a small LDS transpose buffer, then runs 20 padded
// 16x16x16 MFMAs (A rows 3-15 garbage -> discarded D rows) against Bf1.
// h1 never touches global memory; replaces k_edge0 + k_mm1.
// ---------------------------------------------------------------------------
__global__ __launch_bounds__(256) void k_edge0mm(
    const int* __restrict__ off3,
    const unsigned short* __restrict__ pk,
    const float* __restrict__ rg_l,          // [9] layer-0
    const float* __restrict__ sig_l,         // [3*64] layer-0
    const float* __restrict__ ahj4,          // [N*4] layer-0
    const _Float16* __restrict__ hw,         // [N*64]
    const float* __restrict__ x,
    const _Float16* __restrict__ Bf1,        // [80*64] layer-1 B table
    _Float16* __restrict__ hw1,              // [n][3][64] f16
    float* __restrict__ ahj1)                // [N*4]
{
    __shared__ uint4 ent[4][CH];
    __shared__ _Float16 Bt[80][68];
    __shared__ _Float16 As[4][3][68];
    int tid = threadIdx.x, wid = tid >> 6, lane = tid & 63;
    int n = blockIdx.x * 4 + wid;            // NN % 4 == 0

    for (int e4 = tid; e4 < 80 * 64 / 4; e4 += 256) {
        int idx = e4 * 4;
        *(h4*)&Bt[idx >> 6][idx & 63] = *(const h4*)&Bf1[idx];
    }

    int b3 = n * 3;
    int s0 = off3[b3], s1 = off3[b3 + 1], s2 = off3[b3 + 2], s3 = off3[b3 + 3];
    float r00 = rg_l[0], r01 = rg_l[1], r02 = rg_l[2];
    float r10 = rg_l[3], r11 = rg_l[4], r12 = rg_l[5];
    float r20 = rg_l[6], r21 = rg_l[7], r22 = rg_l[8];
    float sg0 = sig_l[lane], sg1 = sig_l[64 + lane], sg2 = sig_l[128 + lane];
    const char* hwb = (const char*)hw + (size_t)lane * 2;
    uint4* myent = ent[wid];
    float acc0 = 0.f, acc1 = 0.f, acc2 = 0.f;
    float ps0 = 0.f, ps1 = 0.f, ps2 = 0.f;

    for (int base = s0; base < s3; base += CH) {
        int cnt = s3 - base; if (cnt > CH) cnt = CH;
        for (int jj = lane; jj < cnt; jj += 64) {
            int ei = base + jj;
            int c = pk[ei];
            int tau = (ei >= s1) + (ei >= s2);
            float4 aj = *(const float4*)&ahj4[c * 4];
            float g0 = (tau == 0) ? r00 : ((tau == 1) ? r01 : r02);
            float g1 = (tau == 0) ? r10 : ((tau == 1) ? r11 : r12);
            float g2 = (tau == 0) ? r20 : ((tau == 1) ? r21 : r22);
            float p0 = __expf(g0 + aj.x);
            float p1 = __expf(g1 + aj.y);
            float p2 = __expf(g2 + aj.z);
            ps0 += p0; ps1 += p1; ps2 += p2;
            myent[jj] = make_uint4(((unsigned)c * 128u) | ((unsigned)tau << 26),
                                   __float_as_uint(p0), __float_as_uint(p1),
                                   __float_as_uint(p2));
        }
        asm volatile("s_waitcnt lgkmcnt(0)" ::: "memory");

#define AGG(J) { uint4 e = myent[J];                                           \
        unsigned ta = e.x >> 26;                                               \
        float sg = (ta == 0) ? sg0 : ((ta == 1) ? sg1 : sg2);                  \
        float sv = sg * (float)*(const _Float16*)(hwb + (e.x & 0x03FFFFFFu));  \
        acc0 = fmaf(__uint_as_float(e.y), sv, acc0);                           \
        acc1 = fmaf(__uint_as_float(e.z), sv, acc1);                           \
        acc2 = fmaf(__uint_as_float(e.w), sv, acc2); }
        int j = 0;
        for (; j + 4 <= cnt; j += 4) { AGG(j) AGG(j + 1) AGG(j + 2) AGG(j + 3) }
        for (; j < cnt; ++j) { AGG(j) }
#undef AGG
        asm volatile("s_waitcnt lgkmcnt(0)" ::: "memory");
    }
    #pragma unroll
    for (int off = 32; off >= 1; off >>= 1) {
        ps0 += __shfl_xor(ps0, off);
        ps1 += __shfl_xor(ps1, off);
        ps2 += __shfl_xor(ps2, off);
    }
    float o0 = 0.f, o1 = 0.f, o2 = 0.f;
    if (s3 > s0) { o0 = acc0 / ps0; o1 = acc1 / ps1; o2 = acc2 / ps2; }
    float xv = x[(size_t)n * 64 + lane];
    As[wid][0][lane] = (_Float16)(xv + fmaxf(o0, 0.f));
    As[wid][1][lane] = (_Float16)(xv + fmaxf(o1, 0.f));
    As[wid][2][lane] = (_Float16)(xv + fmaxf(o2, 0.f));
    __syncthreads();   // orders Bt staging (cross-wave) and As writes

    // layer-1 GEMM on this wave's 3 h1 rows (padded to 16-row MFMA tile)
    int r16 = lane & 15, kq = lane >> 4;
    int ar = (r16 < 3) ? r16 : 0;            // clamp garbage rows in-bounds
    f4 acc[5] = {};
    #pragma unroll
    for (int ks = 0; ks < 4; ++ks) {
        int k0 = ks * 16 + kq * 4;
        h4 a = *(h4*)&As[wid][ar][k0];
        #pragma unroll
        for (int ct = 0; ct < 5; ++ct) {
            h4 bb = *(h4*)&Bt[ct * 16 + r16][k0];
            acc[ct] = __builtin_amdgcn_mfma_f32_16x16x16f16(a, bb, acc[ct], 0, 0, 0);
        }
    }
    // D: col = ct*16 + r16, row = kq*4 + j; rows 0-2 = t
    if (kq == 0) {
        #pragma unroll
        for (int ct = 0; ct < 4; ++ct) {
            hw1[((size_t)n * 3 + 0) * 64 + ct * 16 + r16] = (_Float16)acc[ct][0];
            hw1[((size_t)n * 3 + 1) * 64 + ct * 16 + r16] = (_Float16)acc[ct][1];
            hw1[((size_t)n * 3 + 2) * 64 + ct * 16 + r16] = (_Float16)acc[ct][2];
        }
        if (r16 < 3) {
            float av = (r16 == 0) ? acc[4][0] : ((r16 == 1) ? acc[4][1] : acc[4][2]);
            ahj1[n * 4 + r16] = av;
        }
    }
}

// ---------------------------------------------------------------------------
// k_edge1: layer-1 aggregation (byte-minimal). hw1 [n][3][64] -> 3 f16 loads
// at +0/+128/+256 from one base; flat loop, unroll x8 for MLP.
// ---------------------------------------------------------------------------
__global__ __launch_bounds__(256) void k_edge1(
    const int* __restrict__ off3,
    const unsigned short* __restrict__ pk,
    const float* __restrict__ rg_l,          // [9] layer-1
    const float* __restrict__ sig_l,         // [3*64] layer-1
    const float* __restrict__ ahj4,          // [N*4] layer-1
    const _Float16* __restrict__ hw,         // [N*3*64]
    float* __restrict__ outf)                // [3,N,64] f32
{
    __shared__ uint4 ent[4][CH];
    int wid = threadIdx.x >> 6, lane = threadIdx.x & 63;
    int n = blockIdx.x * 4 + wid;
    int b3 = n * 3;
    int s0 = off3[b3], s1 = off3[b3 + 1], s2 = off3[b3 + 2], s3 = off3[b3 + 3];
    float r00 = rg_l[0], r01 = rg_l[1], r02 = rg_l[2];
    float r10 = rg_l[3], r11 = rg_l[4], r12 = rg_l[5];
    float r20 = rg_l[6], r21 = rg_l[7], r22 = rg_l[8];
    float sg0 = sig_l[lane], sg1 = sig_l[64 + lane], sg2 = sig_l[128 + lane];
    const char* hwb = (const char*)hw + (size_t)lane * 2;
    uint4* myent = ent[wid];
    float acc0 = 0.f, acc1 = 0.f, acc2 = 0.f;
    float ps0 = 0.f, ps1 = 0.f, ps2 = 0.f;

    for (int base = s0; base < s3; base += CH) {
        int cnt = s3 - base; if (cnt > CH) cnt = CH;
        for (int jj = lane; jj < cnt; jj += 64) {
            int ei = base + jj;
            int c = pk[ei];
            int tau = (ei >= s1) + (ei >= s2);
            float4 aj = *(const float4*)&ahj4[c * 4];
            float g0 = (tau == 0) ? r00 : ((tau == 1) ? r01 : r02);
            float g1 = (tau == 0) ? r10 : ((tau == 1) ? r11 : r12);
            float g2 = (tau == 0) ? r20 : ((tau == 1) ? r21 : r22);
            float p0 = __expf(g0 + aj.x);
            float p1 = __expf(g1 + aj.y);
            float p2 = __expf(g2 + aj.z);
            ps0 += p0; ps1 += p1; ps2 += p2;
            myent[jj] = make_uint4(((unsigned)c * 384u) | ((unsigned)tau << 26),
                                   __float_as_uint(p0), __float_as_uint(p1),
                                   __float_as_uint(p2));
        }
        asm volatile("s_waitcnt lgkmcnt(0)" ::: "memory");

#define AGG(J) { uint4 e = myent[J];                                           \
        unsigned ta = e.x >> 26;                                               \
        float sg = (ta == 0) ? sg0 : ((ta == 1) ? sg1 : sg2);                  \
        const char* ptr = hwb + (e.x & 0x03FFFFFFu);                           \
        float v0 = (float)*(const _Float16*)(ptr);                             \
        float v1 = (float)*(const _Float16*)(ptr + 128);                       \
        float v2 = (float)*(const _Float16*)(ptr + 256);                       \
        acc0 = fmaf(__uint_as_float(e.y), sg * v0, acc0);                      \
        acc1 = fmaf(__uint_as_float(e.z), sg * v1, acc1);                      \
        acc2 = fmaf(__uint_as_float(e.w), sg * v2, acc2); }
        int j = 0;
        for (; j + 8 <= cnt; j += 8) { AGG(j) AGG(j + 1) AGG(j + 2) AGG(j + 3)
                                       AGG(j + 4) AGG(j + 5) AGG(j + 6) AGG(j + 7) }
        for (; j + 4 <= cnt; j += 4) { AGG(j) AGG(j + 1) AGG(j + 2) AGG(j + 3) }
        for (; j < cnt; ++j) { AGG(j) }
#undef AGG
        asm volatile("s_waitcnt lgkmcnt(0)" ::: "memory");
    }
    #pragma unroll
    for (int off = 32; off >= 1; off >>= 1) {
        ps0 += __shfl_xor(ps0, off);
        ps1 += __shfl_xor(ps1, off);
        ps2 += __shfl_xor(ps2, off);
    }
    float o0 = 0.f, o1 = 0.f, o2 = 0.f;
    if (s3 > s0) { o0 = acc0 / ps0; o1 = acc1 / ps1; o2 = acc2 / ps2; }
    size_t oi = (size_t)n * 64 + lane;
    outf[oi]                       = o0;
    outf[oi + (size_t)NN * 64]     = o1;
    outf[oi + (size_t)2 * NN * 64] = o2;
}

// ---------------------------------------------------------------------------
extern "C" void kernel_launch(void* const* d_in, const int* in_sizes, int n_in,
                              void* d_out, int out_size, void* d_ws, size_t ws_size,
                              hipStream_t stream)
{
    const float* x   = (const float*)d_in[0];
    const int*   ei  = (const int*)d_in[1];
    const int*   row = ei;
    const int*   col = ei + EE;
    const int*   et  = (const int*)d_in[2];
    const float* ef  = (const float*)d_in[3];
    const float* tg  = (const float*)d_in[4];
    // d_in[5] = theta_hi: cancels in scatter-softmax (constant per group)
    const float* thj = (const float*)d_in[6];
    const float* we  = (const float*)d_in[7];
    const float* wr  = (const float*)d_in[8];
    float* out = (float*)d_out;

    // workspace layout
    _Float16* hw1 = (_Float16*)d_ws;                      // N*3*64
    _Float16* hw0 = hw1 + (size_t)NN * 3 * 64;            // N*64
    float* ahj0 = (float*)(hw0 + (size_t)NN * 64);        // N*4
    float* ahj1 = ahj0 + (size_t)NN * 4;                  // N*4
    float* rg   = ahj1 + (size_t)NN * 4;                  // L*9
    float* sig  = rg + LL * 9;                            // L*192
    _Float16* bfB = (_Float16*)(sig + LL * 192);          // L*80*64 f16
    int* counts3 = (int*)(bfB + LL * 5120);               // NK3
    int* csroff3 = counts3 + NK3;                         // NK3+1
    int* bsum    = csroff3 + NK3 + 1;                     // NB3
    unsigned* keyrank = (unsigned*)(bsum + NB3);          // E
    unsigned short* csrpk = (unsigned short*)(keyrank + EE);  // E

    hipMemsetAsync(counts3, 0, NK3 * sizeof(int), stream);
    // count | layer-0 GEMM | small — independent, one launch
    k_fusedA<<<NBC + NBM + 1, 256, 0, stream>>>(row, et, counts3, keyrank,
                                                x, we, thj, hw0, ahj0,
                                                ef, tg, wr, rg, sig, bfB);
    k_bsum<<<NB3, 256, 0, stream>>>(counts3, bsum);
    k_emit2<<<NB3, 256, 0, stream>>>(counts3, bsum, csroff3);
    k_scatter3r<<<(EE + 255) / 256, 256, 0, stream>>>(keyrank, col, csroff3, csrpk);
    // layer-0 aggregation + in-kernel layer-1 GEMM (h1 stays on-chip)
    k_edge0mm<<<NN / 4, 256, 0, stream>>>(csroff3, csrpk, rg, sig, ahj0, hw0,
                                          x, bfB + 5120, hw1, ahj1);
    // layer-1 aggregation -> final f32 output
    k_edge1<<<NN / 4, 256, 0, stream>>>(csroff3, csrpk, rg + 9, sig + 192,
                                        ahj1, hw1, out);
}

// Round 11
// 179.391 us; speedup vs baseline: 1.1378x; 1.1378x over previous
//
#include <hip/hip_runtime.h>
#include <math.h>

// Problem constants (fixed by the reference setup_inputs()).
#define TT 3
#define NN 50000
#define DD 64
#define EE 800000
#define LL 2
#define NK3 (NN * TT)              // 150000 (row,tau) CSR keys
#define NB3 ((NK3 + 255) / 256)    // 586 scan blocks
#define CH 96                      // edge-walk LDS chunk (>= typical node degree)
#define NBC ((EE + 255) / 256)     // 3125 count blocks
#define NBM ((NN + 63) / 64)       // 782 mm0 blocks

typedef _Float16 h4 __attribute__((ext_vector_type(4)));
typedef float f4 __attribute__((ext_vector_type(4)));

// ---------------------------------------------------------------------------
// k_fusedA: three INDEPENDENT jobs partitioned by blockIdx:
//   [0, NBC)          edge count + keyrank  (atomic rank capture)
//   [NBC, NBC+NBM)    layer-0 GEMM (Bt built from f32 we0/thj0 directly)
//   NBC+NBM           k_small: rg/sig for both layers + f16 B tables
// ---------------------------------------------------------------------------
__global__ __launch_bounds__(256) void k_fusedA(
    const int* __restrict__ row, const int* __restrict__ et,
    int* __restrict__ counts, unsigned* __restrict__ keyrank,
    const float* __restrict__ x,
    const float* __restrict__ we,    // [L,64,64]
    const float* __restrict__ thj,   // [L,3,64]
    _Float16* __restrict__ hw0,      // [N,64]
    float* __restrict__ ahj0,        // [N,4]
    const float* __restrict__ ef0,
    const float* __restrict__ tg,    // [L,T,D]
    const float* __restrict__ wr,    // [L,D,D]
    float* __restrict__ rg,          // [L*9]
    float* __restrict__ sig,         // [L*192]
    _Float16* __restrict__ bf)       // [L*80*64] Bt[c][k] f16
{
    __shared__ _Float16 Ah[64][68];
    __shared__ _Float16 Bt[80][68];
    int b = blockIdx.x, tid = threadIdx.x;

    if (b < NBC) {
        int e = b * 256 + tid;
        if (e < EE) {
            int key = row[e] * 3 + et[e];
            int r = atomicAdd(&counts[key], 1);
            keyrank[e] = ((unsigned)key << 14) | (unsigned)r;  // rank < 16384
        }
        return;
    }
    if (b < NBC + NBM) {
        // ---- layer-0 GEMM: C[N,80] = x @ [we0 | thj0 | 0] ----
        long rbase = (long)(b - NBC) * 64;
        #pragma unroll
        for (int it = 0; it < 4; ++it) {
            int flat = (tid + it * 256) * 4;
            int r = flat >> 6, k = flat & 63;
            h4 hv = {};
            if (rbase + r < NN) {
                float4 v = *(const float4*)&x[(rbase + r) * 64 + k];
                hv = h4{ (_Float16)v.x, (_Float16)v.y, (_Float16)v.z, (_Float16)v.w };
            }
            *(h4*)&Ah[r][k] = hv;
        }
        for (int idx = tid; idx < 80 * 64; idx += 256) {
            int c = idx >> 6, k = idx & 63;
            float v = 0.f;
            if (c < 64) v = we[k * 64 + c];
            else if (c < 67) v = thj[(c - 64) * 64 + k];
            Bt[c][k] = (_Float16)v;
        }
        __syncthreads();
        int wid = tid >> 6, lane = tid & 63;
        int r16 = lane & 15, kq = lane >> 4;
        f4 acc[5] = {};
        #pragma unroll
        for (int ks = 0; ks < 4; ++ks) {
            int k0 = ks * 16 + kq * 4;
            h4 a = *(h4*)&Ah[wid * 16 + r16][k0];
            #pragma unroll
            for (int ct = 0; ct < 5; ++ct) {
                h4 bb = *(h4*)&Bt[ct * 16 + r16][k0];
                acc[ct] = __builtin_amdgcn_mfma_f32_16x16x16f16(a, bb, acc[ct], 0, 0, 0);
            }
        }
        #pragma unroll
        for (int j = 0; j < 4; ++j) {
            long g = rbase + wid * 16 + kq * 4 + j;
            if (g < NN) {
                #pragma unroll
                for (int ct = 0; ct < 4; ++ct)
                    hw0[g * 64 + ct * 16 + r16] = (_Float16)acc[ct][j];
                if (r16 < 3) ahj0[g * 4 + r16] = acc[4][j];
            }
        }
        return;
    }
    // ---- k_small (1 block): rg/sig both layers + f16 B tables ----
    float* ef_l = (float*)&Ah[0][0];
    float* efn  = ef_l + TT * DD;
    for (int l = 0; l < LL; ++l)
        for (int idx = tid; idx < 80 * 64; idx += 256) {
            int c = idx >> 6, k = idx & 63;
            float v = 0.f;
            if (c < 64) v = we[l * 4096 + k * 64 + c];
            else if (c < 67) v = thj[l * 192 + (c - 64) * 64 + k];
            bf[l * 5120 + idx] = (_Float16)v;
        }
    if (tid < TT * DD) ef_l[tid] = ef0[tid];
    __syncthreads();
    for (int layer = 0; layer < LL; ++layer) {
        if (tid < TT * TT) {
            int t = tid / TT, tau = tid % TT;
            float s = 0.f;
            #pragma unroll
            for (int k = 0; k < DD; ++k)
                s += ef_l[tau * DD + k] * tg[layer * TT * DD + t * DD + k];
            rg[layer * TT * TT + tid] = s;
        }
        if (tid < TT * DD) {
            int tau = tid / DD, d = tid % DD;
            float s = 0.f;
            #pragma unroll
            for (int k = 0; k < DD; ++k)
                s += ef_l[tau * DD + k] * wr[layer * DD * DD + k * DD + d];
            efn[tid] = s;
            sig[layer * TT * DD + tid] = 1.f / (1.f + expf(-s));
        }
        __syncthreads();
        if (tid < TT * DD) ef_l[tid] = fmaxf(efn[tid], 0.f);
        __syncthreads();
    }
}

// ---------------------------------------------------------------------------
// CSR scan + emit + atomic-free scatter.
// ---------------------------------------------------------------------------
__global__ void k_bsum(const int* __restrict__ counts, int* __restrict__ bsum)
{
    __shared__ int red[256];
    int i = blockIdx.x * 256 + threadIdx.x;
    red[threadIdx.x] = (i < NK3) ? counts[i] : 0;
    __syncthreads();
    for (int off = 128; off >= 1; off >>= 1) {
        if (threadIdx.x < off) red[threadIdx.x] += red[threadIdx.x + off];
        __syncthreads();
    }
    if (threadIdx.x == 0) bsum[blockIdx.x] = red[0];
}

__global__ void k_emit2(const int* __restrict__ counts,
                        const int* __restrict__ bsum,
                        int* __restrict__ csroff)
{
    __shared__ int s[256];
    __shared__ int bpre_s;
    int b = blockIdx.x, tid = threadIdx.x;
    int pp = 0;
    for (int i = tid; i < b; i += 256) pp += bsum[i];
    s[tid] = pp;
    __syncthreads();
    for (int off = 128; off >= 1; off >>= 1) {
        if (tid < off) s[tid] += s[tid + off];
        __syncthreads();
    }
    if (tid == 0) bpre_s = s[0];
    __syncthreads();
    int bpre = bpre_s;
    int idx = b * 256 + tid;
    int c = (idx < NK3) ? counts[idx] : 0;
    s[tid] = c;
    __syncthreads();
    for (int off = 1; off < 256; off <<= 1) {
        int u = (tid >= off) ? s[tid - off] : 0;
        __syncthreads();
        s[tid] += u;
        __syncthreads();
    }
    if (idx < NK3) csroff[idx] = bpre + s[tid] - c;
    if (b == NB3 - 1 && tid == 255) csroff[NK3] = bpre + s[255];
}

__global__ void k_scatter3r(const unsigned* __restrict__ keyrank,
                            const int* __restrict__ col,
                            const int* __restrict__ csroff,
                            unsigned short* __restrict__ pk)
{
    int e = blockIdx.x * 256 + threadIdx.x;
    if (e < EE) {
        unsigned kr = keyrank[e];
        int pos = csroff[kr >> 14] + (int)(kr & 16383u);
        pk[pos] = (unsigned short)col[e];   // col < 50000 < 2^16
    }
}

// ---------------------------------------------------------------------------
// k_mm1: layer-1 GEMM. Reads h1 (f16, staged in d_out, rows = t*N+n),
// writes hw1 [n][3][64] f16 + ahj1 [n][4].
// ---------------------------------------------------------------------------
__global__ __launch_bounds__(256) void k_mm1(
    const _Float16* __restrict__ h,
    const _Float16* __restrict__ Bf,
    _Float16* __restrict__ hw,
    float* __restrict__ ahj)
{
    __shared__ _Float16 Ah[64][68];
    __shared__ _Float16 Bt[80][68];
    int tid = threadIdx.x;
    long rbase = (long)blockIdx.x * 64;

    #pragma unroll
    for (int it = 0; it < 4; ++it) {
        int flat = (tid + it * 256) * 4;
        int r = flat >> 6, k = flat & 63;
        h4 hv = {};
        if (rbase + r < NK3) hv = *(const h4*)&h[(rbase + r) * 64 + k];
        *(h4*)&Ah[r][k] = hv;
    }
    for (int e4 = tid; e4 < 80 * 64 / 4; e4 += 256) {
        int idx = e4 * 4;
        *(h4*)&Bt[idx >> 6][idx & 63] = *(const h4*)&Bf[idx];
    }
    __syncthreads();

    int wid = tid >> 6, lane = tid & 63;
    int r16 = lane & 15, kq = lane >> 4;
    f4 acc[5] = {};
    #pragma unroll
    for (int ks = 0; ks < 4; ++ks) {
        int k0 = ks * 16 + kq * 4;
        h4 a = *(h4*)&Ah[wid * 16 + r16][k0];
        #pragma unroll
        for (int ct = 0; ct < 5; ++ct) {
            h4 b = *(h4*)&Bt[ct * 16 + r16][k0];
            acc[ct] = __builtin_amdgcn_mfma_f32_16x16x16f16(a, b, acc[ct], 0, 0, 0);
        }
    }
    #pragma unroll
    for (int j = 0; j < 4; ++j) {
        long g = rbase + wid * 16 + kq * 4 + j;
        if (g < NK3) {
            int t = (g >= 2L * NN) ? 2 : (g >= NN ? 1 : 0);
            long n = g - (long)t * NN;
            #pragma unroll
            for (int ct = 0; ct < 4; ++ct)
                hw[((size_t)n * 3 + t) * 64 + ct * 16 + r16] = (_Float16)acc[ct][j];
            if (r16 == t) ahj[n * 4 + t] = acc[4][j];
        }
    }
}

// ---------------------------------------------------------------------------
// k_edge0: layer-0 aggregation. One node per wave, all 3 t's; hw0 [N][64]
// t-invariant -> 1 gather feeds 3 accumulators. Flat loop, unroll x8/x4.
// Writes h1 = x + relu(o) as f16 into d_out.
// ---------------------------------------------------------------------------
__global__ __launch_bounds__(256) void k_edge0(
    const int* __restrict__ off3,
    const unsigned short* __restrict__ pk,
    const float* __restrict__ rg_l,          // [9] layer-0
    const float* __restrict__ sig_l,         // [3*64] layer-0
    const float* __restrict__ ahj4,          // [N*4] layer-0
    const _Float16* __restrict__ hw,         // [N*64]
    const float* __restrict__ x,
    _Float16* __restrict__ outh)             // h1 f16 [3,N,64]
{
    __shared__ uint4 ent[4][CH];
    int wid = threadIdx.x >> 6, lane = threadIdx.x & 63;
    int n = blockIdx.x * 4 + wid;            // NN % 4 == 0
    int b3 = n * 3;
    int s0 = off3[b3], s1 = off3[b3 + 1], s2 = off3[b3 + 2], s3 = off3[b3 + 3];
    float r00 = rg_l[0], r01 = rg_l[1], r02 = rg_l[2];
    float r10 = rg_l[3], r11 = rg_l[4], r12 = rg_l[5];
    float r20 = rg_l[6], r21 = rg_l[7], r22 = rg_l[8];
    float sg0 = sig_l[lane], sg1 = sig_l[64 + lane], sg2 = sig_l[128 + lane];
    const char* hwb = (const char*)hw + (size_t)lane * 2;
    uint4* myent = ent[wid];
    float acc0 = 0.f, acc1 = 0.f, acc2 = 0.f;
    float ps0 = 0.f, ps1 = 0.f, ps2 = 0.f;

    for (int base = s0; base < s3; base += CH) {
        int cnt = s3 - base; if (cnt > CH) cnt = CH;
        for (int jj = lane; jj < cnt; jj += 64) {
            int ei = base + jj;
            int c = pk[ei];
            int tau = (ei >= s1) + (ei >= s2);
            float4 aj = *(const float4*)&ahj4[c * 4];
            float g0 = (tau == 0) ? r00 : ((tau == 1) ? r01 : r02);
            float g1 = (tau == 0) ? r10 : ((tau == 1) ? r11 : r12);
            float g2 = (tau == 0) ? r20 : ((tau == 1) ? r21 : r22);
            float p0 = __expf(g0 + aj.x);
            float p1 = __expf(g1 + aj.y);
            float p2 = __expf(g2 + aj.z);
            ps0 += p0; ps1 += p1; ps2 += p2;
            myent[jj] = make_uint4(((unsigned)c * 128u) | ((unsigned)tau << 26),
                                   __float_as_uint(p0), __float_as_uint(p1),
                                   __float_as_uint(p2));
        }
        asm volatile("s_waitcnt lgkmcnt(0)" ::: "memory");

#define AGG(J) { uint4 e = myent[J];                                           \
        unsigned ta = e.x >> 26;                                               \
        float sg = (ta == 0) ? sg0 : ((ta == 1) ? sg1 : sg2);                  \
        float sv = sg * (float)*(const _Float16*)(hwb + (e.x & 0x03FFFFFFu));  \
        acc0 = fmaf(__uint_as_float(e.y), sv, acc0);                           \
        acc1 = fmaf(__uint_as_float(e.z), sv, acc1);                           \
        acc2 = fmaf(__uint_as_float(e.w), sv, acc2); }
        int j = 0;
        for (; j + 8 <= cnt; j += 8) { AGG(j) AGG(j + 1) AGG(j + 2) AGG(j + 3)
                                       AGG(j + 4) AGG(j + 5) AGG(j + 6) AGG(j + 7) }
        for (; j + 4 <= cnt; j += 4) { AGG(j) AGG(j + 1) AGG(j + 2) AGG(j + 3) }
        for (; j < cnt; ++j) { AGG(j) }
#undef AGG
        asm volatile("s_waitcnt lgkmcnt(0)" ::: "memory");
    }
    #pragma unroll
    for (int off = 32; off >= 1; off >>= 1) {
        ps0 += __shfl_xor(ps0, off);
        ps1 += __shfl_xor(ps1, off);
        ps2 += __shfl_xor(ps2, off);
    }
    float o0 = 0.f, o1 = 0.f, o2 = 0.f;
    if (s3 > s0) { o0 = acc0 / ps0; o1 = acc1 / ps1; o2 = acc2 / ps2; }
    size_t oi = (size_t)n * 64 + lane;
    float xv = x[oi];
    outh[oi]                       = (_Float16)(xv + fmaxf(o0, 0.f));
    outh[oi + (size_t)NN * 64]     = (_Float16)(xv + fmaxf(o1, 0.f));
    outh[oi + (size_t)2 * NN * 64] = (_Float16)(xv + fmaxf(o2, 0.f));
}

// ---------------------------------------------------------------------------
// k_edge1: layer-1 aggregation (byte-minimal). hw1 [n][3][64] -> 3 f16 loads
// at +0/+128/+256 from one base; flat loop, unroll x8.
// ---------------------------------------------------------------------------
__global__ __launch_bounds__(256) void k_edge1(
    const int* __restrict__ off3,
    const unsigned short* __restrict__ pk,
    const float* __restrict__ rg_l,          // [9] layer-1
    const float* __restrict__ sig_l,         // [3*64] layer-1
    const float* __restrict__ ahj4,          // [N*4] layer-1
    const _Float16* __restrict__ hw,         // [N*3*64]
    float* __restrict__ outf)                // [3,N,64] f32
{
    __shared__ uint4 ent[4][CH];
    int wid = threadIdx.x >> 6, lane = threadIdx.x & 63;
    int n = blockIdx.x * 4 + wid;
    int b3 = n * 3;
    int s0 = off3[b3], s1 = off3[b3 + 1], s2 = off3[b3 + 2], s3 = off3[b3 + 3];
    float r00 = rg_l[0], r01 = rg_l[1], r02 = rg_l[2];
    float r10 = rg_l[3], r11 = rg_l[4], r12 = rg_l[5];
    float r20 = rg_l[6], r21 = rg_l[7], r22 = rg_l[8];
    float sg0 = sig_l[lane], sg1 = sig_l[64 + lane], sg2 = sig_l[128 + lane];
    const char* hwb = (const char*)hw + (size_t)lane * 2;
    uint4* myent = ent[wid];
    float acc0 = 0.f, acc1 = 0.f, acc2 = 0.f;
    float ps0 = 0.f, ps1 = 0.f, ps2 = 0.f;

    for (int base = s0; base < s3; base += CH) {
        int cnt = s3 - base; if (cnt > CH) cnt = CH;
        for (int jj = lane; jj < cnt; jj += 64) {
            int ei = base + jj;
            int c = pk[ei];
            int tau = (ei >= s1) + (ei >= s2);
            float4 aj = *(const float4*)&ahj4[c * 4];
            float g0 = (tau == 0) ? r00 : ((tau == 1) ? r01 : r02);
            float g1 = (tau == 0) ? r10 : ((tau == 1) ? r11 : r12);
            float g2 = (tau == 0) ? r20 : ((tau == 1) ? r21 : r22);
            float p0 = __expf(g0 + aj.x);
            float p1 = __expf(g1 + aj.y);
            float p2 = __expf(g2 + aj.z);
            ps0 += p0; ps1 += p1; ps2 += p2;
            myent[jj] = make_uint4(((unsigned)c * 384u) | ((unsigned)tau << 26),
                                   __float_as_uint(p0), __float_as_uint(p1),
                                   __float_as_uint(p2));
        }
        asm volatile("s_waitcnt lgkmcnt(0)" ::: "memory");

#define AGG(J) { uint4 e = myent[J];                                           \
        unsigned ta = e.x >> 26;                                               \
        float sg = (ta == 0) ? sg0 : ((ta == 1) ? sg1 : sg2);                  \
        const char* ptr = hwb + (e.x & 0x03FFFFFFu);                           \
        float v0 = (float)*(const _Float16*)(ptr);                             \
        float v1 = (float)*(const _Float16*)(ptr + 128);                       \
        float v2 = (float)*(const _Float16*)(ptr + 256);                       \
        acc0 = fmaf(__uint_as_float(e.y), sg * v0, acc0);                      \
        acc1 = fmaf(__uint_as_float(e.z), sg * v1, acc1);                      \
        acc2 = fmaf(__uint_as_float(e.w), sg * v2, acc2); }
        int j = 0;
        for (; j + 8 <= cnt; j += 8) { AGG(j) AGG(j + 1) AGG(j + 2) AGG(j + 3)
                                       AGG(j + 4) AGG(j + 5) AGG(j + 6) AGG(j + 7) }
        for (; j + 4 <= cnt; j += 4) { AGG(j) AGG(j + 1) AGG(j + 2) AGG(j + 3) }
        for (; j < cnt; ++j) { AGG(j) }
#undef AGG
        asm volatile("s_waitcnt lgkmcnt(0)" ::: "memory");
    }
    #pragma unroll
    for (int off = 32; off >= 1; off >>= 1) {
        ps0 += __shfl_xor(ps0, off);
        ps1 += __shfl_xor(ps1, off);
        ps2 += __shfl_xor(ps2, off);
    }
    float o0 = 0.f, o1 = 0.f, o2 = 0.f;
    if (s3 > s0) { o0 = acc0 / ps0; o1 = acc1 / ps1; o2 = acc2 / ps2; }
    size_t oi = (size_t)n * 64 + lane;
    outf[oi]                       = o0;
    outf[oi + (size_t)NN * 64]     = o1;
    outf[oi + (size_t)2 * NN * 64] = o2;
}

// ---------------------------------------------------------------------------
extern "C" void kernel_launch(void* const* d_in, const int* in_sizes, int n_in,
                              void* d_out, int out_size, void* d_ws, size_t ws_size,
                              hipStream_t stream)
{
    const float* x   = (const float*)d_in[0];
    const int*   ei  = (const int*)d_in[1];
    const int*   row = ei;
    const int*   col = ei + EE;
    const int*   et  = (const int*)d_in[2];
    const float* ef  = (const float*)d_in[3];
    const float* tg  = (const float*)d_in[4];
    // d_in[5] = theta_hi: cancels in scatter-softmax (constant per group)
    const float* thj = (const float*)d_in[6];
    const float* we  = (const float*)d_in[7];
    const float* wr  = (const float*)d_in[8];
    float* out = (float*)d_out;
    _Float16* h1h = (_Float16*)d_out;   // h1 staged as f16 in d_out

    // workspace layout
    _Float16* hw1 = (_Float16*)d_ws;                      // N*3*64
    _Float16* hw0 = hw1 + (size_t)NN * 3 * 64;            // N*64
    float* ahj0 = (float*)(hw0 + (size_t)NN * 64);        // N*4
    float* ahj1 = ahj0 + (size_t)NN * 4;                  // N*4
    float* rg   = ahj1 + (size_t)NN * 4;                  // L*9
    float* sig  = rg + LL * 9;                            // L*192
    _Float16* bfB = (_Float16*)(sig + LL * 192);          // L*80*64 f16
    int* counts3 = (int*)(bfB + LL * 5120);               // NK3
    int* csroff3 = counts3 + NK3;                         // NK3+1
    int* bsum    = csroff3 + NK3 + 1;                     // NB3
    unsigned* keyrank = (unsigned*)(bsum + NB3);          // E
    unsigned short* csrpk = (unsigned short*)(keyrank + EE);  // E

    hipMemsetAsync(counts3, 0, NK3 * sizeof(int), stream);
    // count | layer-0 GEMM | small — independent, one launch
    k_fusedA<<<NBC + NBM + 1, 256, 0, stream>>>(row, et, counts3, keyrank,
                                                x, we, thj, hw0, ahj0,
                                                ef, tg, wr, rg, sig, bfB);
    k_bsum<<<NB3, 256, 0, stream>>>(counts3, bsum);
    k_emit2<<<NB3, 256, 0, stream>>>(counts3, bsum, csroff3);
    k_scatter3r<<<(EE + 255) / 256, 256, 0, stream>>>(keyrank, col, csroff3, csrpk);
    // layer-0 aggregation -> h1 f16 staged in d_out
    k_edge0<<<NN / 4, 256, 0, stream>>>(csroff3, csrpk, rg, sig, ahj0, hw0,
                                        x, h1h);
    // layer-1 GEMM: hw1 = h1@we1 (f16, [n][3][64]), ahj1
    k_mm1<<<(NK3 + 63) / 64, 256, 0, stream>>>(h1h, bfB + 5120, hw1, ahj1);
    // layer-1 aggregation -> final f32 output
    k_edge1<<<NN / 4, 256, 0, stream>>>(csroff3, csrpk, rg + 9, sig + 192,
                                        ahj1, hw1, out);
}

// Round 12
// 173.515 us; speedup vs baseline: 1.1763x; 1.0339x over previous
//
#include <hip/hip_runtime.h>
#include <math.h>

// Problem constants (fixed by the reference setup_inputs()).
#define TT 3
#define NN 50000
#define DD 64
#define EE 800000
#define LL 2
#define NK3 (NN * TT)              // 150000 (row,tau) CSR keys
#define NB3 ((NK3 + 255) / 256)    // 586 scan blocks
#define CH 96                      // edge-walk LDS chunk (>= typical node degree)
#define NBC ((EE + 255) / 256)     // 3125 count blocks
#define NBM ((NN + 63) / 64)       // 782 mm0 blocks

typedef _Float16 h4 __attribute__((ext_vector_type(4)));
typedef float f4 __attribute__((ext_vector_type(4)));

// ---------------------------------------------------------------------------
// k_fusedA: three INDEPENDENT jobs partitioned by blockIdx:
//   [0, NBC)          edge count + keyrank  (atomic rank capture)
//   [NBC, NBC+NBM)    layer-0 GEMM (Bt built from f32 we0/thj0 directly)
//   NBC+NBM           k_small: rg/sig for both layers + f16 B tables
// ---------------------------------------------------------------------------
__global__ __launch_bounds__(256) void k_fusedA(
    const int* __restrict__ row, const int* __restrict__ et,
    int* __restrict__ counts, unsigned* __restrict__ keyrank,
    const float* __restrict__ x,
    const float* __restrict__ we,    // [L,64,64]
    const float* __restrict__ thj,   // [L,3,64]
    _Float16* __restrict__ hw0,      // [N,64]
    float* __restrict__ ahj0,        // [N,4]
    const float* __restrict__ ef0,
    const float* __restrict__ tg,    // [L,T,D]
    const float* __restrict__ wr,    // [L,D,D]
    float* __restrict__ rg,          // [L*9]
    float* __restrict__ sig,         // [L*192]
    _Float16* __restrict__ bf)       // [L*80*64] Bt[c][k] f16
{
    __shared__ _Float16 Ah[64][68];
    __shared__ _Float16 Bt[80][68];
    int b = blockIdx.x, tid = threadIdx.x;

    if (b < NBC) {
        int e = b * 256 + tid;
        if (e < EE) {
            int key = row[e] * 3 + et[e];
            int r = atomicAdd(&counts[key], 1);
            keyrank[e] = ((unsigned)key << 14) | (unsigned)r;  // rank < 16384
        }
        return;
    }
    if (b < NBC + NBM) {
        // ---- layer-0 GEMM: C[N,80] = x @ [we0 | thj0 | 0] ----
        long rbase = (long)(b - NBC) * 64;
        #pragma unroll
        for (int it = 0; it < 4; ++it) {
            int flat = (tid + it * 256) * 4;
            int r = flat >> 6, k = flat & 63;
            h4 hv = {};
            if (rbase + r < NN) {
                float4 v = *(const float4*)&x[(rbase + r) * 64 + k];
                hv = h4{ (_Float16)v.x, (_Float16)v.y, (_Float16)v.z, (_Float16)v.w };
            }
            *(h4*)&Ah[r][k] = hv;
        }
        for (int idx = tid; idx < 80 * 64; idx += 256) {
            int c = idx >> 6, k = idx & 63;
            float v = 0.f;
            if (c < 64) v = we[k * 64 + c];
            else if (c < 67) v = thj[(c - 64) * 64 + k];
            Bt[c][k] = (_Float16)v;
        }
        __syncthreads();
        int wid = tid >> 6, lane = tid & 63;
        int r16 = lane & 15, kq = lane >> 4;
        f4 acc[5] = {};
        #pragma unroll
        for (int ks = 0; ks < 4; ++ks) {
            int k0 = ks * 16 + kq * 4;
            h4 a = *(h4*)&Ah[wid * 16 + r16][k0];
            #pragma unroll
            for (int ct = 0; ct < 5; ++ct) {
                h4 bb = *(h4*)&Bt[ct * 16 + r16][k0];
                acc[ct] = __builtin_amdgcn_mfma_f32_16x16x16f16(a, bb, acc[ct], 0, 0, 0);
            }
        }
        #pragma unroll
        for (int j = 0; j < 4; ++j) {
            long g = rbase + wid * 16 + kq * 4 + j;
            if (g < NN) {
                #pragma unroll
                for (int ct = 0; ct < 4; ++ct)
                    hw0[g * 64 + ct * 16 + r16] = (_Float16)acc[ct][j];
                if (r16 < 3) ahj0[g * 4 + r16] = acc[4][j];
            }
        }
        return;
    }
    // ---- k_small (1 block): rg/sig both layers + f16 B tables ----
    float* ef_l = (float*)&Ah[0][0];
    float* efn  = ef_l + TT * DD;
    for (int l = 0; l < LL; ++l)
        for (int idx = tid; idx < 80 * 64; idx += 256) {
            int c = idx >> 6, k = idx & 63;
            float v = 0.f;
            if (c < 64) v = we[l * 4096 + k * 64 + c];
            else if (c < 67) v = thj[l * 192 + (c - 64) * 64 + k];
            bf[l * 5120 + idx] = (_Float16)v;
        }
    if (tid < TT * DD) ef_l[tid] = ef0[tid];
    __syncthreads();
    for (int layer = 0; layer < LL; ++layer) {
        if (tid < TT * TT) {
            int t = tid / TT, tau = tid % TT;
            float s = 0.f;
            #pragma unroll
            for (int k = 0; k < DD; ++k)
                s += ef_l[tau * DD + k] * tg[layer * TT * DD + t * DD + k];
            rg[layer * TT * TT + tid] = s;
        }
        if (tid < TT * DD) {
            int tau = tid / DD, d = tid % DD;
            float s = 0.f;
            #pragma unroll
            for (int k = 0; k < DD; ++k)
                s += ef_l[tau * DD + k] * wr[layer * DD * DD + k * DD + d];
            efn[tid] = s;
            sig[layer * TT * DD + tid] = 1.f / (1.f + expf(-s));
        }
        __syncthreads();
        if (tid < TT * DD) ef_l[tid] = fmaxf(efn[tid], 0.f);
        __syncthreads();
    }
}

// ---------------------------------------------------------------------------
// CSR scan + emit + atomic-free scatter.
// ---------------------------------------------------------------------------
__global__ void k_bsum(const int* __restrict__ counts, int* __restrict__ bsum)
{
    __shared__ int red[256];
    int i = blockIdx.x * 256 + threadIdx.x;
    red[threadIdx.x] = (i < NK3) ? counts[i] : 0;
    __syncthreads();
    for (int off = 128; off >= 1; off >>= 1) {
        if (threadIdx.x < off) red[threadIdx.x] += red[threadIdx.x + off];
        __syncthreads();
    }
    if (threadIdx.x == 0) bsum[blockIdx.x] = red[0];
}

__global__ void k_emit2(const int* __restrict__ counts,
                        const int* __restrict__ bsum,
                        int* __restrict__ csroff)
{
    __shared__ int s[256];
    __shared__ int bpre_s;
    int b = blockIdx.x, tid = threadIdx.x;
    int pp = 0;
    for (int i = tid; i < b; i += 256) pp += bsum[i];
    s[tid] = pp;
    __syncthreads();
    for (int off = 128; off >= 1; off >>= 1) {
        if (tid < off) s[tid] += s[tid + off];
        __syncthreads();
    }
    if (tid == 0) bpre_s = s[0];
    __syncthreads();
    int bpre = bpre_s;
    int idx = b * 256 + tid;
    int c = (idx < NK3) ? counts[idx] : 0;
    s[tid] = c;
    __syncthreads();
    for (int off = 1; off < 256; off <<= 1) {
        int u = (tid >= off) ? s[tid - off] : 0;
        __syncthreads();
        s[tid] += u;
        __syncthreads();
    }
    if (idx < NK3) csroff[idx] = bpre + s[tid] - c;
    if (b == NB3 - 1 && tid == 255) csroff[NK3] = bpre + s[255];
}

__global__ void k_scatter3r(const unsigned* __restrict__ keyrank,
                            const int* __restrict__ col,
                            const int* __restrict__ csroff,
                            unsigned short* __restrict__ pk)
{
    int e = blockIdx.x * 256 + threadIdx.x;
    if (e < EE) {
        unsigned kr = keyrank[e];
        int pos = csroff[kr >> 14] + (int)(kr & 16383u);
        pk[pos] = (unsigned short)col[e];   // col < 50000 < 2^16
    }
}

// ---------------------------------------------------------------------------
// k_mm1: layer-1 GEMM. Reads h1 (f16, staged in d_out, rows = t*N+n),
// writes hw1 [n][3][64] f16 + ahj1 [n][4].
// ---------------------------------------------------------------------------
__global__ __launch_bounds__(256) void k_mm1(
    const _Float16* __restrict__ h,
    const _Float16* __restrict__ Bf,
    _Float16* __restrict__ hw,
    float* __restrict__ ahj)
{
    __shared__ _Float16 Ah[64][68];
    __shared__ _Float16 Bt[80][68];
    int tid = threadIdx.x;
    long rbase = (long)blockIdx.x * 64;

    #pragma unroll
    for (int it = 0; it < 4; ++it) {
        int flat = (tid + it * 256) * 4;
        int r = flat >> 6, k = flat & 63;
        h4 hv = {};
        if (rbase + r < NK3) hv = *(const h4*)&h[(rbase + r) * 64 + k];
        *(h4*)&Ah[r][k] = hv;
    }
    for (int e4 = tid; e4 < 80 * 64 / 4; e4 += 256) {
        int idx = e4 * 4;
        *(h4*)&Bt[idx >> 6][idx & 63] = *(const h4*)&Bf[idx];
    }
    __syncthreads();

    int wid = tid >> 6, lane = tid & 63;
    int r16 = lane & 15, kq = lane >> 4;
    f4 acc[5] = {};
    #pragma unroll
    for (int ks = 0; ks < 4; ++ks) {
        int k0 = ks * 16 + kq * 4;
        h4 a = *(h4*)&Ah[wid * 16 + r16][k0];
        #pragma unroll
        for (int ct = 0; ct < 5; ++ct) {
            h4 b = *(h4*)&Bt[ct * 16 + r16][k0];
            acc[ct] = __builtin_amdgcn_mfma_f32_16x16x16f16(a, b, acc[ct], 0, 0, 0);
        }
    }
    #pragma unroll
    for (int j = 0; j < 4; ++j) {
        long g = rbase + wid * 16 + kq * 4 + j;
        if (g < NK3) {
            int t = (g >= 2L * NN) ? 2 : (g >= NN ? 1 : 0);
            long n = g - (long)t * NN;
            #pragma unroll
            for (int ct = 0; ct < 4; ++ct)
                hw[((size_t)n * 3 + t) * 64 + ct * 16 + r16] = (_Float16)acc[ct][j];
            if (r16 == t) ahj[n * 4 + t] = acc[4][j];
        }
    }
}

// ---------------------------------------------------------------------------
// k_edge0: layer-0 aggregation. One node per wave, all 3 t's; hw0 [N][64]
// t-invariant -> 1 gather feeds 3 accumulators. Flat loop, unroll x4
// (x8 costs 12 VGPR -> occupancy 67%->43%, net loss — R11 lesson).
// Writes h1 = x + relu(o) as f16 into d_out.
// ---------------------------------------------------------------------------
__global__ __launch_bounds__(256) void k_edge0(
    const int* __restrict__ off3,
    const unsigned short* __restrict__ pk,
    const float* __restrict__ rg_l,          // [9] layer-0
    const float* __restrict__ sig_l,         // [3*64] layer-0
    const float* __restrict__ ahj4,          // [N*4] layer-0
    const _Float16* __restrict__ hw,         // [N*64]
    const float* __restrict__ x,
    _Float16* __restrict__ outh)             // h1 f16 [3,N,64]
{
    __shared__ uint4 ent[4][CH];
    int wid = threadIdx.x >> 6, lane = threadIdx.x & 63;
    int n = blockIdx.x * 4 + wid;            // NN % 4 == 0
    int b3 = n * 3;
    int s0 = off3[b3], s1 = off3[b3 + 1], s2 = off3[b3 + 2], s3 = off3[b3 + 3];
    float r00 = rg_l[0], r01 = rg_l[1], r02 = rg_l[2];
    float r10 = rg_l[3], r11 = rg_l[4], r12 = rg_l[5];
    float r20 = rg_l[6], r21 = rg_l[7], r22 = rg_l[8];
    float sg0 = sig_l[lane], sg1 = sig_l[64 + lane], sg2 = sig_l[128 + lane];
    const char* hwb = (const char*)hw + (size_t)lane * 2;
    uint4* myent = ent[wid];
    float acc0 = 0.f, acc1 = 0.f, acc2 = 0.f;
    float ps0 = 0.f, ps1 = 0.f, ps2 = 0.f;

    for (int base = s0; base < s3; base += CH) {
        int cnt = s3 - base; if (cnt > CH) cnt = CH;
        for (int jj = lane; jj < cnt; jj += 64) {
            int ei = base + jj;
            int c = pk[ei];
            int tau = (ei >= s1) + (ei >= s2);
            float4 aj = *(const float4*)&ahj4[c * 4];
            float g0 = (tau == 0) ? r00 : ((tau == 1) ? r01 : r02);
            float g1 = (tau == 0) ? r10 : ((tau == 1) ? r11 : r12);
            float g2 = (tau == 0) ? r20 : ((tau == 1) ? r21 : r22);
            float p0 = __expf(g0 + aj.x);
            float p1 = __expf(g1 + aj.y);
            float p2 = __expf(g2 + aj.z);
            ps0 += p0; ps1 += p1; ps2 += p2;
            myent[jj] = make_uint4(((unsigned)c * 128u) | ((unsigned)tau << 26),
                                   __float_as_uint(p0), __float_as_uint(p1),
                                   __float_as_uint(p2));
        }
        asm volatile("s_waitcnt lgkmcnt(0)" ::: "memory");

#define AGG(J) { uint4 e = myent[J];                                           \
        unsigned ta = e.x >> 26;                                               \
        float sg = (ta == 0) ? sg0 : ((ta == 1) ? sg1 : sg2);                  \
        float sv = sg * (float)*(const _Float16*)(hwb + (e.x & 0x03FFFFFFu));  \
        acc0 = fmaf(__uint_as_float(e.y), sv, acc0);                           \
        acc1 = fmaf(__uint_as_float(e.z), sv, acc1);                           \
        acc2 = fmaf(__uint_as_float(e.w), sv, acc2); }
        int j = 0;
        for (; j + 4 <= cnt; j += 4) { AGG(j) AGG(j + 1) AGG(j + 2) AGG(j + 3) }
        for (; j < cnt; ++j) { AGG(j) }
#undef AGG
        asm volatile("s_waitcnt lgkmcnt(0)" ::: "memory");
    }
    #pragma unroll
    for (int off = 32; off >= 1; off >>= 1) {
        ps0 += __shfl_xor(ps0, off);
        ps1 += __shfl_xor(ps1, off);
        ps2 += __shfl_xor(ps2, off);
    }
    float o0 = 0.f, o1 = 0.f, o2 = 0.f;
    if (s3 > s0) { o0 = acc0 / ps0; o1 = acc1 / ps1; o2 = acc2 / ps2; }
    size_t oi = (size_t)n * 64 + lane;
    float xv = x[oi];
    outh[oi]                       = (_Float16)(xv + fmaxf(o0, 0.f));
    outh[oi + (size_t)NN * 64]     = (_Float16)(xv + fmaxf(o1, 0.f));
    outh[oi + (size_t)2 * NN * 64] = (_Float16)(xv + fmaxf(o2, 0.f));
}

// ---------------------------------------------------------------------------
// k_edge1: layer-1 aggregation (byte-minimal). hw1 [n][3][64] -> 3 f16 loads
// at +0/+128/+256 from one base; flat loop, unroll x4 (32 VGPR, ~67% occ —
// the x8 variant's 44 VGPR dropped occupancy to 43% and cost 10 µs, R11).
// ---------------------------------------------------------------------------
__global__ __launch_bounds__(256) void k_edge1(
    const int* __restrict__ off3,
    const unsigned short* __restrict__ pk,
    const float* __restrict__ rg_l,          // [9] layer-1
    const float* __restrict__ sig_l,         // [3*64] layer-1
    const float* __restrict__ ahj4,          // [N*4] layer-1
    const _Float16* __restrict__ hw,         // [N*3*64]
    float* __restrict__ outf)                // [3,N,64] f32
{
    __shared__ uint4 ent[4][CH];
    int wid = threadIdx.x >> 6, lane = threadIdx.x & 63;
    int n = blockIdx.x * 4 + wid;
    int b3 = n * 3;
    int s0 = off3[b3], s1 = off3[b3 + 1], s2 = off3[b3 + 2], s3 = off3[b3 + 3];
    float r00 = rg_l[0], r01 = rg_l[1], r02 = rg_l[2];
    float r10 = rg_l[3], r11 = rg_l[4], r12 = rg_l[5];
    float r20 = rg_l[6], r21 = rg_l[7], r22 = rg_l[8];
    float sg0 = sig_l[lane], sg1 = sig_l[64 + lane], sg2 = sig_l[128 + lane];
    const char* hwb = (const char*)hw + (size_t)lane * 2;
    uint4* myent = ent[wid];
    float acc0 = 0.f, acc1 = 0.f, acc2 = 0.f;
    float ps0 = 0.f, ps1 = 0.f, ps2 = 0.f;

    for (int base = s0; base < s3; base += CH) {
        int cnt = s3 - base; if (cnt > CH) cnt = CH;
        for (int jj = lane; jj < cnt; jj += 64) {
            int ei = base + jj;
            int c = pk[ei];
            int tau = (ei >= s1) + (ei >= s2);
            float4 aj = *(const float4*)&ahj4[c * 4];
            float g0 = (tau == 0) ? r00 : ((tau == 1) ? r01 : r02);
            float g1 = (tau == 0) ? r10 : ((tau == 1) ? r11 : r12);
            float g2 = (tau == 0) ? r20 : ((tau == 1) ? r21 : r22);
            float p0 = __expf(g0 + aj.x);
            float p1 = __expf(g1 + aj.y);
            float p2 = __expf(g2 + aj.z);
            ps0 += p0; ps1 += p1; ps2 += p2;
            myent[jj] = make_uint4(((unsigned)c * 384u) | ((unsigned)tau << 26),
                                   __float_as_uint(p0), __float_as_uint(p1),
                                   __float_as_uint(p2));
        }
        asm volatile("s_waitcnt lgkmcnt(0)" ::: "memory");

#define AGG(J) { uint4 e = myent[J];                                           \
        unsigned ta = e.x >> 26;                                               \
        float sg = (ta == 0) ? sg0 : ((ta == 1) ? sg1 : sg2);                  \
        const char* ptr = hwb + (e.x & 0x03FFFFFFu);                           \
        float v0 = (float)*(const _Float16*)(ptr);                             \
        float v1 = (float)*(const _Float16*)(ptr + 128);                       \
        float v2 = (float)*(const _Float16*)(ptr + 256);                       \
        acc0 = fmaf(__uint_as_float(e.y), sg * v0, acc0);                      \
        acc1 = fmaf(__uint_as_float(e.z), sg * v1, acc1);                      \
        acc2 = fmaf(__uint_as_float(e.w), sg * v2, acc2); }
        int j = 0;
        for (; j + 4 <= cnt; j += 4) { AGG(j) AGG(j + 1) AGG(j + 2) AGG(j + 3) }
        for (; j < cnt; ++j) { AGG(j) }
#undef AGG
        asm volatile("s_waitcnt lgkmcnt(0)" ::: "memory");
    }
    #pragma unroll
    for (int off = 32; off >= 1; off >>= 1) {
        ps0 += __shfl_xor(ps0, off);
        ps1 += __shfl_xor(ps1, off);
        ps2 += __shfl_xor(ps2, off);
    }
    float o0 = 0.f, o1 = 0.f, o2 = 0.f;
    if (s3 > s0) { o0 = acc0 / ps0; o1 = acc1 / ps1; o2 = acc2 / ps2; }
    size_t oi = (size_t)n * 64 + lane;
    outf[oi]                       = o0;
    outf[oi + (size_t)NN * 64]     = o1;
    outf[oi + (size_t)2 * NN * 64] = o2;
}

// ---------------------------------------------------------------------------
extern "C" void kernel_launch(void* const* d_in, const int* in_sizes, int n_in,
                              void* d_out, int out_size, void* d_ws, size_t ws_size,
                              hipStream_t stream)
{
    const float* x   = (const float*)d_in[0];
    const int*   ei  = (const int*)d_in[1];
    const int*   row = ei;
    const int*   col = ei + EE;
    const int*   et  = (const int*)d_in[2];
    const float* ef  = (const float*)d_in[3];
    const float* tg  = (const float*)d_in[4];
    // d_in[5] = theta_hi: cancels in scatter-softmax (constant per group)
    const float* thj = (const float*)d_in[6];
    const float* we  = (const float*)d_in[7];
    const float* wr  = (const float*)d_in[8];
    float* out = (float*)d_out;
    _Float16* h1h = (_Float16*)d_out;   // h1 staged as f16 in d_out

    // workspace layout
    _Float16* hw1 = (_Float16*)d_ws;                      // N*3*64
    _Float16* hw0 = hw1 + (size_t)NN * 3 * 64;            // N*64
    float* ahj0 = (float*)(hw0 + (size_t)NN * 64);        // N*4
    float* ahj1 = ahj0 + (size_t)NN * 4;                  // N*4
    float* rg   = ahj1 + (size_t)NN * 4;                  // L*9
    float* sig  = rg + LL * 9;                            // L*192
    _Float16* bfB = (_Float16*)(sig + LL * 192);          // L*80*64 f16
    int* counts3 = (int*)(bfB + LL * 5120);               // NK3
    int* csroff3 = counts3 + NK3;                         // NK3+1
    int* bsum    = csroff3 + NK3 + 1;                     // NB3
    unsigned* keyrank = (unsigned*)(bsum + NB3);          // E
    unsigned short* csrpk = (unsigned short*)(keyrank + EE);  // E

    hipMemsetAsync(counts3, 0, NK3 * sizeof(int), stream);
    // count | layer-0 GEMM | small — independent, one launch
    k_fusedA<<<NBC + NBM + 1, 256, 0, stream>>>(row, et, counts3, keyrank,
                                                x, we, thj, hw0, ahj0,
                                                ef, tg, wr, rg, sig, bfB);
    k_bsum<<<NB3, 256, 0, stream>>>(counts3, bsum);
    k_emit2<<<NB3, 256, 0, stream>>>(counts3, bsum, csroff3);
    k_scatter3r<<<(EE + 255) / 256, 256, 0, stream>>>(keyrank, col, csroff3, csrpk);
    // layer-0 aggregation -> h1 f16 staged in d_out
    k_edge0<<<NN / 4, 256, 0, stream>>>(csroff3, csrpk, rg, sig, ahj0, hw0,
                                        x, h1h);
    // layer-1 GEMM: hw1 = h1@we1 (f16, [n][3][64]), ahj1
    k_mm1<<<(NK3 + 63) / 64, 256, 0, stream>>>(h1h, bfB + 5120, hw1, ahj1);
    // layer-1 aggregation -> final f32 output
    k_edge1<<<NN / 4, 256, 0, stream>>>(csroff3, csrpk, rg + 9, sig + 192,
                                        ahj1, hw1, out);
}

// Round 13
// 170.277 us; speedup vs baseline: 1.1987x; 1.0190x over previous
//
#include <hip/hip_runtime.h>
#include <math.h>

// Problem constants (fixed by the reference setup_inputs()).
#define TT 3
#define NN 50000
#define DD 64
#define EE 800000
#define LL 2
#define NK3 (NN * TT)              // 150000 (row,tau) CSR keys
#define CH 96                      // edge-walk LDS chunk
#define NBC ((EE + 255) / 256)     // 3125 edge blocks (EE%256==0 -> exact)
#define NBM ((NN + 63) / 64)       // 782 mm0 blocks
#define NBKT ((NN + 127) / 128)    // 391 row-buckets (row>>7)
#define KPB 384                    // keys per bucket = 128 rows * 3
#define HP 3136                    // padded block stride (>= NBC, 64-mult)

typedef _Float16 h4 __attribute__((ext_vector_type(4)));
typedef float f4 __attribute__((ext_vector_type(4)));

// ---------------------------------------------------------------------------
// k_fusedA: three INDEPENDENT jobs partitioned by blockIdx:
//   [0, NBC)        pass A: per-block bucket histogram (LDS atomics only)
//   [NBC, NBC+NBM)  layer-0 GEMM
//   NBC+NBM         k_small: rg/sig both layers + f16 B tables
// ---------------------------------------------------------------------------
__global__ __launch_bounds__(256) void k_fusedA(
    const int* __restrict__ row, const int* __restrict__ et,
    int* __restrict__ blockHistT,    // [NBKT][HP]
    const float* __restrict__ x,
    const float* __restrict__ we,    // [L,64,64]
    const float* __restrict__ thj,   // [L,3,64]
    _Float16* __restrict__ hw0,      // [N,64]
    float* __restrict__ ahj0,        // [N,4]
    const float* __restrict__ ef0,
    const float* __restrict__ tg,    // [L,T,D]
    const float* __restrict__ wr,    // [L,D,D]
    float* __restrict__ rg,          // [L*9]
    float* __restrict__ sig,         // [L*192]
    _Float16* __restrict__ bf)       // [L*80*64] Bt[c][k] f16
{
    __shared__ _Float16 Ah[64][68];
    __shared__ _Float16 Bt[80][68];
    __shared__ int lhist[NBKT];
    int b = blockIdx.x, tid = threadIdx.x;

    if (b < NBC) {
        // ---- pass A: bucket histogram for this block's 256 edges ----
        for (int i = tid; i < NBKT; i += 256) lhist[i] = 0;
        __syncthreads();
        int e = b * 256 + tid;           // always valid (EE%256==0)
        int bkt = row[e] >> 7;
        atomicAdd(&lhist[bkt], 1);       // LDS atomic
        __syncthreads();
        for (int i = tid; i < NBKT; i += 256)
            blockHistT[(size_t)i * HP + b] = lhist[i];
        return;
    }
    if (b < NBC + NBM) {
        // ---- layer-0 GEMM: C[N,80] = x @ [we0 | thj0 | 0] ----
        long rbase = (long)(b - NBC) * 64;
        #pragma unroll
        for (int it = 0; it < 4; ++it) {
            int flat = (tid + it * 256) * 4;
            int r = flat >> 6, k = flat & 63;
            h4 hv = {};
            if (rbase + r < NN) {
                float4 v = *(const float4*)&x[(rbase + r) * 64 + k];
                hv = h4{ (_Float16)v.x, (_Float16)v.y, (_Float16)v.z, (_Float16)v.w };
            }
            *(h4*)&Ah[r][k] = hv;
        }
        for (int idx = tid; idx < 80 * 64; idx += 256) {
            int c = idx >> 6, k = idx & 63;
            float v = 0.f;
            if (c < 64) v = we[k * 64 + c];
            else if (c < 67) v = thj[(c - 64) * 64 + k];
            Bt[c][k] = (_Float16)v;
        }
        __syncthreads();
        int wid = tid >> 6, lane = tid & 63;
        int r16 = lane & 15, kq = lane >> 4;
        f4 acc[5] = {};
        #pragma unroll
        for (int ks = 0; ks < 4; ++ks) {
            int k0 = ks * 16 + kq * 4;
            h4 a = *(h4*)&Ah[wid * 16 + r16][k0];
            #pragma unroll
            for (int ct = 0; ct < 5; ++ct) {
                h4 bb = *(h4*)&Bt[ct * 16 + r16][k0];
                acc[ct] = __builtin_amdgcn_mfma_f32_16x16x16f16(a, bb, acc[ct], 0, 0, 0);
            }
        }
        #pragma unroll
        for (int j = 0; j < 4; ++j) {
            long g = rbase + wid * 16 + kq * 4 + j;
            if (g < NN) {
                #pragma unroll
                for (int ct = 0; ct < 4; ++ct)
                    hw0[g * 64 + ct * 16 + r16] = (_Float16)acc[ct][j];
                if (r16 < 3) ahj0[g * 4 + r16] = acc[4][j];
            }
        }
        return;
    }
    // ---- k_small (1 block) ----
    float* ef_l = (float*)&Ah[0][0];
    float* efn  = ef_l + TT * DD;
    for (int l = 0; l < LL; ++l)
        for (int idx = tid; idx < 80 * 64; idx += 256) {
            int c = idx >> 6, k = idx & 63;
            float v = 0.f;
            if (c < 64) v = we[l * 4096 + k * 64 + c];
            else if (c < 67) v = thj[l * 192 + (c - 64) * 64 + k];
            bf[l * 5120 + idx] = (_Float16)v;
        }
    if (tid < TT * DD) ef_l[tid] = ef0[tid];
    __syncthreads();
    for (int layer = 0; layer < LL; ++layer) {
        if (tid < TT * TT) {
            int t = tid / TT, tau = tid % TT;
            float s = 0.f;
            #pragma unroll
            for (int k = 0; k < DD; ++k)
                s += ef_l[tau * DD + k] * tg[layer * TT * DD + t * DD + k];
            rg[layer * TT * TT + tid] = s;
        }
        if (tid < TT * DD) {
            int tau = tid / DD, d = tid % DD;
            float s = 0.f;
            #pragma unroll
            for (int k = 0; k < DD; ++k)
                s += ef_l[tau * DD + k] * wr[layer * DD * DD + k * DD + d];
            efn[tid] = s;
            sig[layer * TT * DD + tid] = 1.f / (1.f + expf(-s));
        }
        __syncthreads();
        if (tid < TT * DD) ef_l[tid] = fmaxf(efn[tid], 0.f);
        __syncthreads();
    }
}

// ---------------------------------------------------------------------------
// pass B: per-bucket exclusive scan over block histograms (in place) + totals.
// ---------------------------------------------------------------------------
__global__ __launch_bounds__(256) void k_colscan(
    int* __restrict__ blockHistT, int* __restrict__ bucketTotal)
{
    __shared__ int sc[256];
    __shared__ int carryB;
    int j = blockIdx.x, tid = threadIdx.x;
    int* colp = blockHistT + (size_t)j * HP;
    if (tid == 0) carryB = 0;
    __syncthreads();
    for (int c0 = 0; c0 < NBC; c0 += 256) {
        int b = c0 + tid;
        int v = (b < NBC) ? colp[b] : 0;
        sc[tid] = v;
        __syncthreads();
        for (int off = 1; off < 256; off <<= 1) {
            int u = (tid >= off) ? sc[tid - off] : 0;
            __syncthreads();
            sc[tid] += u;
            __syncthreads();
        }
        int cb = carryB;
        if (b < NBC) colp[b] = cb + sc[tid] - v;   // exclusive over blocks
        __syncthreads();
        if (tid == 0) carryB = cb + sc[255];
        __syncthreads();
    }
    if (tid == 0) bucketTotal[j] = carryB;
}

// ---------------------------------------------------------------------------
// pass C: scatter edges into bucket-sorted order. NO global atomics —
// rank within (block,bucket) via LDS atomic; position = bucketBase +
// blockOffset + rank. Record = keyLocal<<16 | col.
// ---------------------------------------------------------------------------
__global__ __launch_bounds__(256) void k_bucket(
    const int* __restrict__ row, const int* __restrict__ et,
    const int* __restrict__ col,
    const int* __restrict__ bucketTotal,
    const int* __restrict__ blockOffT,    // scanned blockHistT
    unsigned* __restrict__ bucketed)
{
    __shared__ int lrank[NBKT];
    __shared__ int lbase[NBKT];
    __shared__ int sc[256];
    __shared__ int carryC;
    int b = blockIdx.x, tid = threadIdx.x;
    for (int i = tid; i < NBKT; i += 256) lrank[i] = 0;
    if (tid == 0) carryC = 0;
    __syncthreads();
    // exclusive scan of bucketTotal -> lbase (L2-hot, 391 ints)
    for (int c0 = 0; c0 < NBKT; c0 += 256) {
        int i = c0 + tid;
        int v = (i < NBKT) ? bucketTotal[i] : 0;
        sc[tid] = v;
        __syncthreads();
        for (int off = 1; off < 256; off <<= 1) {
            int u = (tid >= off) ? sc[tid - off] : 0;
            __syncthreads();
            sc[tid] += u;
            __syncthreads();
        }
        int cb = carryC;
        if (i < NBKT) lbase[i] = cb + sc[tid] - v;
        __syncthreads();
        if (tid == 0) carryC = cb + sc[255];
        __syncthreads();
    }
    int e = b * 256 + tid;               // always valid
    int r = row[e], tt = et[e], c = col[e];
    int bkt = r >> 7;
    int kl = (r - (bkt << 7)) * 3 + tt;  // keyLocal < 384
    int rk = atomicAdd(&lrank[bkt], 1);  // LDS atomic
    int pos = lbase[bkt] + blockOffT[(size_t)bkt * HP + b] + rk;
    bucketed[pos] = ((unsigned)kl << 16) | (unsigned)c;
}

// ---------------------------------------------------------------------------
// pass D: per-bucket CSR emit. counts/scan/rank all in LDS. Bucket j owns
// keys [j*384, j*384+384) (contiguous); csroff[NK3] falls out naturally at
// bucket 390, keyLocal 240.
// ---------------------------------------------------------------------------
__global__ __launch_bounds__(256) void k_emit3(
    const unsigned* __restrict__ bucketed,
    const int* __restrict__ bucketTotal,
    int* __restrict__ csroff,
    unsigned short* __restrict__ pk)
{
    __shared__ int counts[KPB];
    __shared__ int csr[KPB];
    __shared__ int sc[256];
    __shared__ int carryS;
    int j = blockIdx.x, tid = threadIdx.x;
    // base = sum of bucketTotal[0..j)
    int pp = 0;
    for (int i = tid; i < j; i += 256) pp += bucketTotal[i];
    sc[tid] = pp;
    __syncthreads();
    for (int off = 128; off >= 1; off >>= 1) {
        if (tid < off) sc[tid] += sc[tid + off];
        __syncthreads();
    }
    int base = sc[0];
    int tot = bucketTotal[j];
    __syncthreads();
    for (int k = tid; k < KPB; k += 256) counts[k] = 0;
    if (tid == 0) carryS = 0;
    __syncthreads();
    // phase 1: count
    for (int i = tid; i < tot; i += 256) {
        int kl = (int)(bucketed[base + i] >> 16);
        atomicAdd(&counts[kl], 1);
    }
    __syncthreads();
    // phase 2: exclusive scan counts -> csr; write csroff
    for (int c0 = 0; c0 < KPB; c0 += 256) {
        int k = c0 + tid;
        int v = (k < KPB) ? counts[k] : 0;
        sc[tid] = v;
        __syncthreads();
        for (int off = 1; off < 256; off <<= 1) {
            int u = (tid >= off) ? sc[tid - off] : 0;
            __syncthreads();
            sc[tid] += u;
            __syncthreads();
        }
        int cb = carryS;
        if (k < KPB) csr[k] = cb + sc[tid] - v;
        __syncthreads();
        if (tid == 0) carryS = cb + sc[255];
        __syncthreads();
    }
    for (int k = tid; k < KPB; k += 256) {
        int gk = j * KPB + k;
        if (gk <= NK3) csroff[gk] = base + csr[k];
    }
    for (int k = tid; k < KPB; k += 256) counts[k] = 0;
    __syncthreads();
    // phase 3: fresh LDS ranks + final scatter (order within key arbitrary)
    for (int i = tid; i < tot; i += 256) {
        unsigned rec = bucketed[base + i];
        int kl = (int)(rec >> 16);
        int rk = atomicAdd(&counts[kl], 1);
        pk[base + csr[kl] + rk] = (unsigned short)(rec & 0xFFFFu);
    }
}

// ---------------------------------------------------------------------------
// k_mm1: layer-1 GEMM (unchanged R12).
// ---------------------------------------------------------------------------
__global__ __launch_bounds__(256) void k_mm1(
    const _Float16* __restrict__ h,
    const _Float16* __restrict__ Bf,
    _Float16* __restrict__ hw,
    float* __restrict__ ahj)
{
    __shared__ _Float16 Ah[64][68];
    __shared__ _Float16 Bt[80][68];
    int tid = threadIdx.x;
    long rbase = (long)blockIdx.x * 64;

    #pragma unroll
    for (int it = 0; it < 4; ++it) {
        int flat = (tid + it * 256) * 4;
        int r = flat >> 6, k = flat & 63;
        h4 hv = {};
        if (rbase + r < NK3) hv = *(const h4*)&h[(rbase + r) * 64 + k];
        *(h4*)&Ah[r][k] = hv;
    }
    for (int e4 = tid; e4 < 80 * 64 / 4; e4 += 256) {
        int idx = e4 * 4;
        *(h4*)&Bt[idx >> 6][idx & 63] = *(const h4*)&Bf[idx];
    }
    __syncthreads();

    int wid = tid >> 6, lane = tid & 63;
    int r16 = lane & 15, kq = lane >> 4;
    f4 acc[5] = {};
    #pragma unroll
    for (int ks = 0; ks < 4; ++ks) {
        int k0 = ks * 16 + kq * 4;
        h4 a = *(h4*)&Ah[wid * 16 + r16][k0];
        #pragma unroll
        for (int ct = 0; ct < 5; ++ct) {
            h4 b = *(h4*)&Bt[ct * 16 + r16][k0];
            acc[ct] = __builtin_amdgcn_mfma_f32_16x16x16f16(a, b, acc[ct], 0, 0, 0);
        }
    }
    #pragma unroll
    for (int j = 0; j < 4; ++j) {
        long g = rbase + wid * 16 + kq * 4 + j;
        if (g < NK3) {
            int t = (g >= 2L * NN) ? 2 : (g >= NN ? 1 : 0);
            long n = g - (long)t * NN;
            #pragma unroll
            for (int ct = 0; ct < 4; ++ct)
                hw[((size_t)n * 3 + t) * 64 + ct * 16 + r16] = (_Float16)acc[ct][j];
            if (r16 == t) ahj[n * 4 + t] = acc[4][j];
        }
    }
}

// ---------------------------------------------------------------------------
// k_edge0: layer-0 aggregation (unchanged R12: x4 unroll, 32 VGPR).
// ---------------------------------------------------------------------------
__global__ __launch_bounds__(256) void k_edge0(
    const int* __restrict__ off3,
    const unsigned short* __restrict__ pk,
    const float* __restrict__ rg_l,
    const float* __restrict__ sig_l,
    const float* __restrict__ ahj4,
    const _Float16* __restrict__ hw,
    const float* __restrict__ x,
    _Float16* __restrict__ outh)
{
    __shared__ uint4 ent[4][CH];
    int wid = threadIdx.x >> 6, lane = threadIdx.x & 63;
    int n = blockIdx.x * 4 + wid;
    int b3 = n * 3;
    int s0 = off3[b3], s1 = off3[b3 + 1], s2 = off3[b3 + 2], s3 = off3[b3 + 3];
    float r00 = rg_l[0], r01 = rg_l[1], r02 = rg_l[2];
    float r10 = rg_l[3], r11 = rg_l[4], r12 = rg_l[5];
    float r20 = rg_l[6], r21 = rg_l[7], r22 = rg_l[8];
    float sg0 = sig_l[lane], sg1 = sig_l[64 + lane], sg2 = sig_l[128 + lane];
    const char* hwb = (const char*)hw + (size_t)lane * 2;
    uint4* myent = ent[wid];
    float acc0 = 0.f, acc1 = 0.f, acc2 = 0.f;
    float ps0 = 0.f, ps1 = 0.f, ps2 = 0.f;

    for (int base = s0; base < s3; base += CH) {
        int cnt = s3 - base; if (cnt > CH) cnt = CH;
        for (int jj = lane; jj < cnt; jj += 64) {
            int ei = base + jj;
            int c = pk[ei];
            int tau = (ei >= s1) + (ei >= s2);
            float4 aj = *(const float4*)&ahj4[c * 4];
            float g0 = (tau == 0) ? r00 : ((tau == 1) ? r01 : r02);
            float g1 = (tau == 0) ? r10 : ((tau == 1) ? r11 : r12);
            float g2 = (tau == 0) ? r20 : ((tau == 1) ? r21 : r22);
            float p0 = __expf(g0 + aj.x);
            float p1 = __expf(g1 + aj.y);
            float p2 = __expf(g2 + aj.z);
            ps0 += p0; ps1 += p1; ps2 += p2;
            myent[jj] = make_uint4(((unsigned)c * 128u) | ((unsigned)tau << 26),
                                   __float_as_uint(p0), __float_as_uint(p1),
                                   __float_as_uint(p2));
        }
        asm volatile("s_waitcnt lgkmcnt(0)" ::: "memory");

#define AGG(J) { uint4 e = myent[J];                                           \
        unsigned ta = e.x >> 26;                                               \
        float sg = (ta == 0) ? sg0 : ((ta == 1) ? sg1 : sg2);                  \
        float sv = sg * (float)*(const _Float16*)(hwb + (e.x & 0x03FFFFFFu));  \
        acc0 = fmaf(__uint_as_float(e.y), sv, acc0);                           \
        acc1 = fmaf(__uint_as_float(e.z), sv, acc1);                           \
        acc2 = fmaf(__uint_as_float(e.w), sv, acc2); }
        int j = 0;
        for (; j + 4 <= cnt; j += 4) { AGG(j) AGG(j + 1) AGG(j + 2) AGG(j + 3) }
        for (; j < cnt; ++j) { AGG(j) }
#undef AGG
        asm volatile("s_waitcnt lgkmcnt(0)" ::: "memory");
    }
    #pragma unroll
    for (int off = 32; off >= 1; off >>= 1) {
        ps0 += __shfl_xor(ps0, off);
        ps1 += __shfl_xor(ps1, off);
        ps2 += __shfl_xor(ps2, off);
    }
    float o0 = 0.f, o1 = 0.f, o2 = 0.f;
    if (s3 > s0) { o0 = acc0 / ps0; o1 = acc1 / ps1; o2 = acc2 / ps2; }
    size_t oi = (size_t)n * 64 + lane;
    float xv = x[oi];
    outh[oi]                       = (_Float16)(xv + fmaxf(o0, 0.f));
    outh[oi + (size_t)NN * 64]     = (_Float16)(xv + fmaxf(o1, 0.f));
    outh[oi + (size_t)2 * NN * 64] = (_Float16)(xv + fmaxf(o2, 0.f));
}

// ---------------------------------------------------------------------------
// k_edge1: layer-1 aggregation (unchanged R12: x4 unroll, 32 VGPR).
// ---------------------------------------------------------------------------
__global__ __launch_bounds__(256) void k_edge1(
    const int* __restrict__ off3,
    const unsigned short* __restrict__ pk,
    const float* __restrict__ rg_l,
    const float* __restrict__ sig_l,
    const float* __restrict__ ahj4,
    const _Float16* __restrict__ hw,
    float* __restrict__ outf)
{
    __shared__ uint4 ent[4][CH];
    int wid = threadIdx.x >> 6, lane = threadIdx.x & 63;
    int n = blockIdx.x * 4 + wid;
    int b3 = n * 3;
    int s0 = off3[b3], s1 = off3[b3 + 1], s2 = off3[b3 + 2], s3 = off3[b3 + 3];
    float r00 = rg_l[0], r01 = rg_l[1], r02 = rg_l[2];
    float r10 = rg_l[3], r11 = rg_l[4], r12 = rg_l[5];
    float r20 = rg_l[6], r21 = rg_l[7], r22 = rg_l[8];
    float sg0 = sig_l[lane], sg1 = sig_l[64 + lane], sg2 = sig_l[128 + lane];
    const char* hwb = (const char*)hw + (size_t)lane * 2;
    uint4* myent = ent[wid];
    float acc0 = 0.f, acc1 = 0.f, acc2 = 0.f;
    float ps0 = 0.f, ps1 = 0.f, ps2 = 0.f;

    for (int base = s0; base < s3; base += CH) {
        int cnt = s3 - base; if (cnt > CH) cnt = CH;
        for (int jj = lane; jj < cnt; jj += 64) {
            int ei = base + jj;
            int c = pk[ei];
            int tau = (ei >= s1) + (ei >= s2);
            float4 aj = *(const float4*)&ahj4[c * 4];
            float g0 = (tau == 0) ? r00 : ((tau == 1) ? r01 : r02);
            float g1 = (tau == 0) ? r10 : ((tau == 1) ? r11 : r12);
            float g2 = (tau == 0) ? r20 : ((tau == 1) ? r21 : r22);
            float p0 = __expf(g0 + aj.x);
            float p1 = __expf(g1 + aj.y);
            float p2 = __expf(g2 + aj.z);
            ps0 += p0; ps1 += p1; ps2 += p2;
            myent[jj] = make_uint4(((unsigned)c * 384u) | ((unsigned)tau << 26),
                                   __float_as_uint(p0), __float_as_uint(p1),
                                   __float_as_uint(p2));
        }
        asm volatile("s_waitcnt lgkmcnt(0)" ::: "memory");

#define AGG(J) { uint4 e = myent[J];                                           \
        unsigned ta = e.x >> 26;                                               \
        float sg = (ta == 0) ? sg0 : ((ta == 1) ? sg1 : sg2);                  \
        const char* ptr = hwb + (e.x & 0x03FFFFFFu);                           \
        float v0 = (float)*(const _Float16*)(ptr);                             \
        float v1 = (float)*(const _Float16*)(ptr + 128);                       \
        float v2 = (float)*(const _Float16*)(ptr + 256);                       \
        acc0 = fmaf(__uint_as_float(e.y), sg * v0, acc0);                      \
        acc1 = fmaf(__uint_as_float(e.z), sg * v1, acc1);                      \
        acc2 = fmaf(__uint_as_float(e.w), sg * v2, acc2); }
        int j = 0;
        for (; j + 4 <= cnt; j += 4) { AGG(j) AGG(j + 1) AGG(j + 2) AGG(j + 3) }
        for (; j < cnt; ++j) { AGG(j) }
#undef AGG
        asm volatile("s_waitcnt lgkmcnt(0)" ::: "memory");
    }
    #pragma unroll
    for (int off = 32; off >= 1; off >>= 1) {
        ps0 += __shfl_xor(ps0, off);
        ps1 += __shfl_xor(ps1, off);
        ps2 += __shfl_xor(ps2, off);
    }
    float o0 = 0.f, o1 = 0.f, o2 = 0.f;
    if (s3 > s0) { o0 = acc0 / ps0; o1 = acc1 / ps1; o2 = acc2 / ps2; }
    size_t oi = (size_t)n * 64 + lane;
    outf[oi]                       = o0;
    outf[oi + (size_t)NN * 64]     = o1;
    outf[oi + (size_t)2 * NN * 64] = o2;
}

// ---------------------------------------------------------------------------
extern "C" void kernel_launch(void* const* d_in, const int* in_sizes, int n_in,
                              void* d_out, int out_size, void* d_ws, size_t ws_size,
                              hipStream_t stream)
{
    const float* x   = (const float*)d_in[0];
    const int*   ei  = (const int*)d_in[1];
    const int*   row = ei;
    const int*   col = ei + EE;
    const int*   et  = (const int*)d_in[2];
    const float* ef  = (const float*)d_in[3];
    const float* tg  = (const float*)d_in[4];
    // d_in[5] = theta_hi: cancels in scatter-softmax (constant per group)
    const float* thj = (const float*)d_in[6];
    const float* we  = (const float*)d_in[7];
    const float* wr  = (const float*)d_in[8];
    float* out = (float*)d_out;
    _Float16* h1h = (_Float16*)d_out;   // h1 staged as f16 in d_out

    // workspace layout
    _Float16* hw1 = (_Float16*)d_ws;                      // N*3*64 f16
    _Float16* hw0 = hw1 + (size_t)NN * 3 * 64;            // N*64 f16
    float* ahj0 = (float*)(hw0 + (size_t)NN * 64);        // N*4
    float* ahj1 = ahj0 + (size_t)NN * 4;                  // N*4
    float* rg   = ahj1 + (size_t)NN * 4;                  // L*9
    float* sig  = rg + LL * 9;                            // L*192
    _Float16* bfB = (_Float16*)(sig + LL * 192);          // L*80*64 f16
    int* csroff3 = (int*)(bfB + LL * 5120);               // NK3+1
    int* bucketTotal = csroff3 + NK3 + 1;                 // NBKT
    int* blockHistT  = bucketTotal + NBKT;                // NBKT*HP (4.9 MB)
    unsigned* bucketed = (unsigned*)(blockHistT + (size_t)NBKT * HP);  // E
    unsigned short* csrpk = (unsigned short*)(bucketed + EE);          // E

    // pass A | layer-0 GEMM | small — independent, one launch, no atomics
    k_fusedA<<<NBC + NBM + 1, 256, 0, stream>>>(row, et, blockHistT,
                                                x, we, thj, hw0, ahj0,
                                                ef, tg, wr, rg, sig, bfB);
    k_colscan<<<NBKT, 256, 0, stream>>>(blockHistT, bucketTotal);
    k_bucket<<<NBC, 256, 0, stream>>>(row, et, col, bucketTotal, blockHistT,
                                      bucketed);
    k_emit3<<<NBKT, 256, 0, stream>>>(bucketed, bucketTotal, csroff3, csrpk);

    // layer-0 aggregation -> h1 f16 staged in d_out
    k_edge0<<<NN / 4, 256, 0, stream>>>(csroff3, csrpk, rg, sig, ahj0, hw0,
                                        x, h1h);
    // layer-1 GEMM: hw1 = h1@we1 (f16, [n][3][64]), ahj1
    k_mm1<<<(NK3 + 63) / 64, 256, 0, stream>>>(h1h, bfB + 5120, hw1, ahj1);
    // layer-1 aggregation -> final f32 output
    k_edge1<<<NN / 4, 256, 0, stream>>>(csroff3, csrpk, rg + 9, sig + 192,
                                        ahj1, hw1, out);
}

// Round 14
// 146.400 us; speedup vs baseline: 1.3942x; 1.1631x over previous
//
#include <hip/hip_runtime.h>
#include <math.h>

// Problem constants (fixed by the reference setup_inputs()).
#define TT 3
#define NN 50000
#define DD 64
#define EE 800000
#define LL 2
#define NK3 (NN * TT)              // 150000 (row,tau) CSR keys
#define CH 96                      // edge-walk LDS chunk
#define NBM ((NN + 63) / 64)       // 782 mm0 blocks
#define NBKT ((NN + 127) / 128)    // 391 row-buckets (row>>7)
#define KPB 384                    // keys per bucket = 128 rows * 3
#define NB2 256                    // coarse edge blocks (pass A/C)
#define EPB2 (EE / NB2)            // 3125 edges per coarse block (exact)
#define HP2 392                    // padded row stride of blockHist

typedef _Float16 h4 __attribute__((ext_vector_type(4)));
typedef float f4 __attribute__((ext_vector_type(4)));

// ---------------------------------------------------------------------------
// k_fusedA: three INDEPENDENT jobs partitioned by blockIdx:
//   [0, NB2)        pass A: coarse per-block bucket histogram (LDS atomics,
//                   COALESCED row-major write — R13's transposed write was
//                   1.2M scattered stores = ~78 MB of line traffic)
//   [NB2, NB2+NBM)  layer-0 GEMM
//   NB2+NBM         k_small: rg/sig both layers + f16 B tables
// ---------------------------------------------------------------------------
__global__ __launch_bounds__(256) void k_fusedA(
    const int* __restrict__ row, const int* __restrict__ et,
    int* __restrict__ blockHist,     // [NB2][HP2]
    const float* __restrict__ x,
    const float* __restrict__ we,    // [L,64,64]
    const float* __restrict__ thj,   // [L,3,64]
    _Float16* __restrict__ hw0,      // [N,64]
    float* __restrict__ ahj0,        // [N,4]
    const float* __restrict__ ef0,
    const float* __restrict__ tg,    // [L,T,D]
    const float* __restrict__ wr,    // [L,D,D]
    float* __restrict__ rg,          // [L*9]
    float* __restrict__ sig,         // [L*192]
    _Float16* __restrict__ bf)       // [L*80*64] Bt[c][k] f16
{
    __shared__ _Float16 Ah[64][68];
    __shared__ _Float16 Bt[80][68];
    __shared__ int lhist[NBKT];
    int b = blockIdx.x, tid = threadIdx.x;

    if (b < NB2) {
        // ---- pass A: histogram of 3125 edges over 391 buckets ----
        for (int i = tid; i < NBKT; i += 256) lhist[i] = 0;
        __syncthreads();
        int e0 = b * EPB2;
        for (int i = tid; i < EPB2; i += 256)
            atomicAdd(&lhist[row[e0 + i] >> 7], 1);   // LDS atomic
        __syncthreads();
        for (int i = tid; i < NBKT; i += 256)
            blockHist[b * HP2 + i] = lhist[i];        // coalesced
        return;
    }
    if (b < NB2 + NBM) {
        // ---- layer-0 GEMM: C[N,80] = x @ [we0 | thj0 | 0] ----
        long rbase = (long)(b - NB2) * 64;
        #pragma unroll
        for (int it = 0; it < 4; ++it) {
            int flat = (tid + it * 256) * 4;
            int r = flat >> 6, k = flat & 63;
            h4 hv = {};
            if (rbase + r < NN) {
                float4 v = *(const float4*)&x[(rbase + r) * 64 + k];
                hv = h4{ (_Float16)v.x, (_Float16)v.y, (_Float16)v.z, (_Float16)v.w };
            }
            *(h4*)&Ah[r][k] = hv;
        }
        for (int idx = tid; idx < 80 * 64; idx += 256) {
            int c = idx >> 6, k = idx & 63;
            float v = 0.f;
            if (c < 64) v = we[k * 64 + c];
            else if (c < 67) v = thj[(c - 64) * 64 + k];
            Bt[c][k] = (_Float16)v;
        }
        __syncthreads();
        int wid = tid >> 6, lane = tid & 63;
        int r16 = lane & 15, kq = lane >> 4;
        f4 acc[5] = {};
        #pragma unroll
        for (int ks = 0; ks < 4; ++ks) {
            int k0 = ks * 16 + kq * 4;
            h4 a = *(h4*)&Ah[wid * 16 + r16][k0];
            #pragma unroll
            for (int ct = 0; ct < 5; ++ct) {
                h4 bb = *(h4*)&Bt[ct * 16 + r16][k0];
                acc[ct] = __builtin_amdgcn_mfma_f32_16x16x16f16(a, bb, acc[ct], 0, 0, 0);
            }
        }
        #pragma unroll
        for (int j = 0; j < 4; ++j) {
            long g = rbase + wid * 16 + kq * 4 + j;
            if (g < NN) {
                #pragma unroll
                for (int ct = 0; ct < 4; ++ct)
                    hw0[g * 64 + ct * 16 + r16] = (_Float16)acc[ct][j];
                if (r16 < 3) ahj0[g * 4 + r16] = acc[4][j];
            }
        }
        return;
    }
    // ---- k_small (1 block) ----
    float* ef_l = (float*)&Ah[0][0];
    float* efn  = ef_l + TT * DD;
    for (int l = 0; l < LL; ++l)
        for (int idx = tid; idx < 80 * 64; idx += 256) {
            int c = idx >> 6, k = idx & 63;
            float v = 0.f;
            if (c < 64) v = we[l * 4096 + k * 64 + c];
            else if (c < 67) v = thj[l * 192 + (c - 64) * 64 + k];
            bf[l * 5120 + idx] = (_Float16)v;
        }
    if (tid < TT * DD) ef_l[tid] = ef0[tid];
    __syncthreads();
    for (int layer = 0; layer < LL; ++layer) {
        if (tid < TT * TT) {
            int t = tid / TT, tau = tid % TT;
            float s = 0.f;
            #pragma unroll
            for (int k = 0; k < DD; ++k)
                s += ef_l[tau * DD + k] * tg[layer * TT * DD + t * DD + k];
            rg[layer * TT * TT + tid] = s;
        }
        if (tid < TT * DD) {
            int tau = tid / DD, d = tid % DD;
            float s = 0.f;
            #pragma unroll
            for (int k = 0; k < DD; ++k)
                s += ef_l[tau * DD + k] * wr[layer * DD * DD + k * DD + d];
            efn[tid] = s;
            sig[layer * TT * DD + tid] = 1.f / (1.f + expf(-s));
        }
        __syncthreads();
        if (tid < TT * DD) ef_l[tid] = fmaxf(efn[tid], 0.f);
        __syncthreads();
    }
}

// ---------------------------------------------------------------------------
// pass B: per-bucket exclusive scan over the 256 coarse blocks (one chunk).
// ---------------------------------------------------------------------------
__global__ __launch_bounds__(256) void k_colscan(
    int* __restrict__ blockHist, int* __restrict__ bucketTotal)
{
    __shared__ int sc[256];
    int j = blockIdx.x, tid = threadIdx.x;
    int v = blockHist[tid * HP2 + j];        // strided column read (L2-hot)
    sc[tid] = v;
    __syncthreads();
    for (int off = 1; off < 256; off <<= 1) {
        int u = (tid >= off) ? sc[tid - off] : 0;
        __syncthreads();
        sc[tid] += u;
        __syncthreads();
    }
    blockHist[tid * HP2 + j] = sc[tid] - v;  // exclusive over blocks
    if (tid == 255) bucketTotal[j] = sc[255];
}

// ---------------------------------------------------------------------------
// pass C: scatter edges into bucket-sorted order. NO global atomics.
// 256 coarse blocks; rank within (block,bucket) via LDS atomic.
// Record = keyLocal<<16 | col.
// ---------------------------------------------------------------------------
__global__ __launch_bounds__(256) void k_bucket(
    const int* __restrict__ row, const int* __restrict__ et,
    const int* __restrict__ col,
    const int* __restrict__ bucketTotal,
    const int* __restrict__ blockOff,     // scanned blockHist [NB2][HP2]
    unsigned* __restrict__ bucketed)
{
    __shared__ int lrank[NBKT];
    __shared__ int lbase[NBKT];
    __shared__ int sc[256];
    __shared__ int carryC;
    int b = blockIdx.x, tid = threadIdx.x;
    for (int i = tid; i < NBKT; i += 256) lrank[i] = 0;
    if (tid == 0) carryC = 0;
    __syncthreads();
    // exclusive scan of bucketTotal -> lbase (391 ints, 2 chunks)
    for (int c0 = 0; c0 < NBKT; c0 += 256) {
        int i = c0 + tid;
        int v = (i < NBKT) ? bucketTotal[i] : 0;
        sc[tid] = v;
        __syncthreads();
        for (int off = 1; off < 256; off <<= 1) {
            int u = (tid >= off) ? sc[tid - off] : 0;
            __syncthreads();
            sc[tid] += u;
            __syncthreads();
        }
        int cb = carryC;
        if (i < NBKT) lbase[i] = cb + sc[tid] - v;
        __syncthreads();
        if (tid == 0) carryC = cb + sc[255];
        __syncthreads();
    }
    int e0 = b * EPB2;
    for (int i = tid; i < EPB2; i += 256) {
        int e = e0 + i;
        int r = row[e], tt = et[e], c = col[e];
        int bkt = r >> 7;
        int kl = (r - (bkt << 7)) * 3 + tt;   // keyLocal < 384
        int rk = atomicAdd(&lrank[bkt], 1);   // LDS atomic
        int pos = lbase[bkt] + blockOff[b * HP2 + bkt] + rk;
        bucketed[pos] = ((unsigned)kl << 16) | (unsigned)c;
    }
}

// ---------------------------------------------------------------------------
// pass D: per-bucket CSR emit (counts/scan/rank all in LDS).
// ---------------------------------------------------------------------------
__global__ __launch_bounds__(256) void k_emit3(
    const unsigned* __restrict__ bucketed,
    const int* __restrict__ bucketTotal,
    int* __restrict__ csroff,
    unsigned short* __restrict__ pk)
{
    __shared__ int counts[KPB];
    __shared__ int csr[KPB];
    __shared__ int sc[256];
    __shared__ int carryS;
    int j = blockIdx.x, tid = threadIdx.x;
    int pp = 0;
    for (int i = tid; i < j; i += 256) pp += bucketTotal[i];
    sc[tid] = pp;
    __syncthreads();
    for (int off = 128; off >= 1; off >>= 1) {
        if (tid < off) sc[tid] += sc[tid + off];
        __syncthreads();
    }
    int base = sc[0];
    int tot = bucketTotal[j];
    __syncthreads();
    for (int k = tid; k < KPB; k += 256) counts[k] = 0;
    if (tid == 0) carryS = 0;
    __syncthreads();
    for (int i = tid; i < tot; i += 256) {
        int kl = (int)(bucketed[base + i] >> 16);
        atomicAdd(&counts[kl], 1);
    }
    __syncthreads();
    for (int c0 = 0; c0 < KPB; c0 += 256) {
        int k = c0 + tid;
        int v = (k < KPB) ? counts[k] : 0;
        sc[tid] = v;
        __syncthreads();
        for (int off = 1; off < 256; off <<= 1) {
            int u = (tid >= off) ? sc[tid - off] : 0;
            __syncthreads();
            sc[tid] += u;
            __syncthreads();
        }
        int cb = carryS;
        if (k < KPB) csr[k] = cb + sc[tid] - v;
        __syncthreads();
        if (tid == 0) carryS = cb + sc[255];
        __syncthreads();
    }
    for (int k = tid; k < KPB; k += 256) {
        int gk = j * KPB + k;
        if (gk <= NK3) csroff[gk] = base + csr[k];
    }
    for (int k = tid; k < KPB; k += 256) counts[k] = 0;
    __syncthreads();
    for (int i = tid; i < tot; i += 256) {
        unsigned rec = bucketed[base + i];
        int kl = (int)(rec >> 16);
        int rk = atomicAdd(&counts[kl], 1);
        pk[base + csr[kl] + rk] = (unsigned short)(rec & 0xFFFFu);
    }
}

// ---------------------------------------------------------------------------
// k_mm1: layer-1 GEMM (unchanged).
// ---------------------------------------------------------------------------
__global__ __launch_bounds__(256) void k_mm1(
    const _Float16* __restrict__ h,
    const _Float16* __restrict__ Bf,
    _Float16* __restrict__ hw,
    float* __restrict__ ahj)
{
    __shared__ _Float16 Ah[64][68];
    __shared__ _Float16 Bt[80][68];
    int tid = threadIdx.x;
    long rbase = (long)blockIdx.x * 64;

    #pragma unroll
    for (int it = 0; it < 4; ++it) {
        int flat = (tid + it * 256) * 4;
        int r = flat >> 6, k = flat & 63;
        h4 hv = {};
        if (rbase + r < NK3) hv = *(const h4*)&h[(rbase + r) * 64 + k];
        *(h4*)&Ah[r][k] = hv;
    }
    for (int e4 = tid; e4 < 80 * 64 / 4; e4 += 256) {
        int idx = e4 * 4;
        *(h4*)&Bt[idx >> 6][idx & 63] = *(const h4*)&Bf[idx];
    }
    __syncthreads();

    int wid = tid >> 6, lane = tid & 63;
    int r16 = lane & 15, kq = lane >> 4;
    f4 acc[5] = {};
    #pragma unroll
    for (int ks = 0; ks < 4; ++ks) {
        int k0 = ks * 16 + kq * 4;
        h4 a = *(h4*)&Ah[wid * 16 + r16][k0];
        #pragma unroll
        for (int ct = 0; ct < 5; ++ct) {
            h4 b = *(h4*)&Bt[ct * 16 + r16][k0];
            acc[ct] = __builtin_amdgcn_mfma_f32_16x16x16f16(a, b, acc[ct], 0, 0, 0);
        }
    }
    #pragma unroll
    for (int j = 0; j < 4; ++j) {
        long g = rbase + wid * 16 + kq * 4 + j;
        if (g < NK3) {
            int t = (g >= 2L * NN) ? 2 : (g >= NN ? 1 : 0);
            long n = g - (long)t * NN;
            #pragma unroll
            for (int ct = 0; ct < 4; ++ct)
                hw[((size_t)n * 3 + t) * 64 + ct * 16 + r16] = (_Float16)acc[ct][j];
            if (r16 == t) ahj[n * 4 + t] = acc[4][j];
        }
    }
}

// ---------------------------------------------------------------------------
// k_edge0: layer-0 aggregation (unchanged: x4 unroll, 32 VGPR).
// ---------------------------------------------------------------------------
__global__ __launch_bounds__(256) void k_edge0(
    const int* __restrict__ off3,
    const unsigned short* __restrict__ pk,
    const float* __restrict__ rg_l,
    const float* __restrict__ sig_l,
    const float* __restrict__ ahj4,
    const _Float16* __restrict__ hw,
    const float* __restrict__ x,
    _Float16* __restrict__ outh)
{
    __shared__ uint4 ent[4][CH];
    int wid = threadIdx.x >> 6, lane = threadIdx.x & 63;
    int n = blockIdx.x * 4 + wid;
    int b3 = n * 3;
    int s0 = off3[b3], s1 = off3[b3 + 1], s2 = off3[b3 + 2], s3 = off3[b3 + 3];
    float r00 = rg_l[0], r01 = rg_l[1], r02 = rg_l[2];
    float r10 = rg_l[3], r11 = rg_l[4], r12 = rg_l[5];
    float r20 = rg_l[6], r21 = rg_l[7], r22 = rg_l[8];
    float sg0 = sig_l[lane], sg1 = sig_l[64 + lane], sg2 = sig_l[128 + lane];
    const char* hwb = (const char*)hw + (size_t)lane * 2;
    uint4* myent = ent[wid];
    float acc0 = 0.f, acc1 = 0.f, acc2 = 0.f;
    float ps0 = 0.f, ps1 = 0.f, ps2 = 0.f;

    for (int base = s0; base < s3; base += CH) {
        int cnt = s3 - base; if (cnt > CH) cnt = CH;
        for (int jj = lane; jj < cnt; jj += 64) {
            int ei = base + jj;
            int c = pk[ei];
            int tau = (ei >= s1) + (ei >= s2);
            float4 aj = *(const float4*)&ahj4[c * 4];
            float g0 = (tau == 0) ? r00 : ((tau == 1) ? r01 : r02);
            float g1 = (tau == 0) ? r10 : ((tau == 1) ? r11 : r12);
            float g2 = (tau == 0) ? r20 : ((tau == 1) ? r21 : r22);
            float p0 = __expf(g0 + aj.x);
            float p1 = __expf(g1 + aj.y);
            float p2 = __expf(g2 + aj.z);
            ps0 += p0; ps1 += p1; ps2 += p2;
            myent[jj] = make_uint4(((unsigned)c * 128u) | ((unsigned)tau << 26),
                                   __float_as_uint(p0), __float_as_uint(p1),
                                   __float_as_uint(p2));
        }
        asm volatile("s_waitcnt lgkmcnt(0)" ::: "memory");

#define AGG(J) { uint4 e = myent[J];                                           \
        unsigned ta = e.x >> 26;                                               \
        float sg = (ta == 0) ? sg0 : ((ta == 1) ? sg1 : sg2);                  \
        float sv = sg * (float)*(const _Float16*)(hwb + (e.x & 0x03FFFFFFu));  \
        acc0 = fmaf(__uint_as_float(e.y), sv, acc0);                           \
        acc1 = fmaf(__uint_as_float(e.z), sv, acc1);                           \
        acc2 = fmaf(__uint_as_float(e.w), sv, acc2); }
        int j = 0;
        for (; j + 4 <= cnt; j += 4) { AGG(j) AGG(j + 1) AGG(j + 2) AGG(j + 3) }
        for (; j < cnt; ++j) { AGG(j) }
#undef AGG
        asm volatile("s_waitcnt lgkmcnt(0)" ::: "memory");
    }
    #pragma unroll
    for (int off = 32; off >= 1; off >>= 1) {
        ps0 += __shfl_xor(ps0, off);
        ps1 += __shfl_xor(ps1, off);
        ps2 += __shfl_xor(ps2, off);
    }
    float o0 = 0.f, o1 = 0.f, o2 = 0.f;
    if (s3 > s0) { o0 = acc0 / ps0; o1 = acc1 / ps1; o2 = acc2 / ps2; }
    size_t oi = (size_t)n * 64 + lane;
    float xv = x[oi];
    outh[oi]                       = (_Float16)(xv + fmaxf(o0, 0.f));
    outh[oi + (size_t)NN * 64]     = (_Float16)(xv + fmaxf(o1, 0.f));
    outh[oi + (size_t)2 * NN * 64] = (_Float16)(xv + fmaxf(o2, 0.f));
}

// ---------------------------------------------------------------------------
// k_edge1: layer-1 aggregation (unchanged: x4 unroll, 32 VGPR).
// ---------------------------------------------------------------------------
__global__ __launch_bounds__(256) void k_edge1(
    const int* __restrict__ off3,
    const unsigned short* __restrict__ pk,
    const float* __restrict__ rg_l,
    const float* __restrict__ sig_l,
    const float* __restrict__ ahj4,
    const _Float16* __restrict__ hw,
    float* __restrict__ outf)
{
    __shared__ uint4 ent[4][CH];
    int wid = threadIdx.x >> 6, lane = threadIdx.x & 63;
    int n = blockIdx.x * 4 + wid;
    int b3 = n * 3;
    int s0 = off3[b3], s1 = off3[b3 + 1], s2 = off3[b3 + 2], s3 = off3[b3 + 3];
    float r00 = rg_l[0], r01 = rg_l[1], r02 = rg_l[2];
    float r10 = rg_l[3], r11 = rg_l[4], r12 = rg_l[5];
    float r20 = rg_l[6], r21 = rg_l[7], r22 = rg_l[8];
    float sg0 = sig_l[lane], sg1 = sig_l[64 + lane], sg2 = sig_l[128 + lane];
    const char* hwb = (const char*)hw + (size_t)lane * 2;
    uint4* myent = ent[wid];
    float acc0 = 0.f, acc1 = 0.f, acc2 = 0.f;
    float ps0 = 0.f, ps1 = 0.f, ps2 = 0.f;

    for (int base = s0; base < s3; base += CH) {
        int cnt = s3 - base; if (cnt > CH) cnt = CH;
        for (int jj = lane; jj < cnt; jj += 64) {
            int ei = base + jj;
            int c = pk[ei];
            int tau = (ei >= s1) + (ei >= s2);
            float4 aj = *(const float4*)&ahj4[c * 4];
            float g0 = (tau == 0) ? r00 : ((tau == 1) ? r01 : r02);
            float g1 = (tau == 0) ? r10 : ((tau == 1) ? r11 : r12);
            float g2 = (tau == 0) ? r20 : ((tau == 1) ? r21 : r22);
            float p0 = __expf(g0 + aj.x);
            float p1 = __expf(g1 + aj.y);
            float p2 = __expf(g2 + aj.z);
            ps0 += p0; ps1 += p1; ps2 += p2;
            myent[jj] = make_uint4(((unsigned)c * 384u) | ((unsigned)tau << 26),
                                   __float_as_uint(p0), __float_as_uint(p1),
                                   __float_as_uint(p2));
        }
        asm volatile("s_waitcnt lgkmcnt(0)" ::: "memory");

#define AGG(J) { uint4 e = myent[J];                                           \
        unsigned ta = e.x >> 26;                                               \
        float sg = (ta == 0) ? sg0 : ((ta == 1) ? sg1 : sg2);                  \
        const char* ptr = hwb + (e.x & 0x03FFFFFFu);                           \
        float v0 = (float)*(const _Float16*)(ptr);                             \
        float v1 = (float)*(const _Float16*)(ptr + 128);                       \
        float v2 = (float)*(const _Float16*)(ptr + 256);                       \
        acc0 = fmaf(__uint_as_float(e.y), sg * v0, acc0);                      \
        acc1 = fmaf(__uint_as_float(e.z), sg * v1, acc1);                      \
        acc2 = fmaf(__uint_as_float(e.w), sg * v2, acc2); }
        int j = 0;
        for (; j + 4 <= cnt; j += 4) { AGG(j) AGG(j + 1) AGG(j + 2) AGG(j + 3) }
        for (; j < cnt; ++j) { AGG(j) }
#undef AGG
        asm volatile("s_waitcnt lgkmcnt(0)" ::: "memory");
    }
    #pragma unroll
    for (int off = 32; off >= 1; off >>= 1) {
        ps0 += __shfl_xor(ps0, off);
        ps1 += __shfl_xor(ps1, off);
        ps2 += __shfl_xor(ps2, off);
    }
    float o0 = 0.f, o1 = 0.f, o2 = 0.f;
    if (s3 > s0) { o0 = acc0 / ps0; o1 = acc1 / ps1; o2 = acc2 / ps2; }
    size_t oi = (size_t)n * 64 + lane;
    outf[oi]                       = o0;
    outf[oi + (size_t)NN * 64]     = o1;
    outf[oi + (size_t)2 * NN * 64] = o2;
}

// ---------------------------------------------------------------------------
extern "C" void kernel_launch(void* const* d_in, const int* in_sizes, int n_in,
                              void* d_out, int out_size, void* d_ws, size_t ws_size,
                              hipStream_t stream)
{
    const float* x   = (const float*)d_in[0];
    const int*   ei  = (const int*)d_in[1];
    const int*   row = ei;
    const int*   col = ei + EE;
    const int*   et  = (const int*)d_in[2];
    const float* ef  = (const float*)d_in[3];
    const float* tg  = (const float*)d_in[4];
    // d_in[5] = theta_hi: cancels in scatter-softmax (constant per group)
    const float* thj = (const float*)d_in[6];
    const float* we  = (const float*)d_in[7];
    const float* wr  = (const float*)d_in[8];
    float* out = (float*)d_out;
    _Float16* h1h = (_Float16*)d_out;   // h1 staged as f16 in d_out

    // workspace layout
    _Float16* hw1 = (_Float16*)d_ws;                      // N*3*64 f16
    _Float16* hw0 = hw1 + (size_t)NN * 3 * 64;            // N*64 f16
    float* ahj0 = (float*)(hw0 + (size_t)NN * 64);        // N*4
    float* ahj1 = ahj0 + (size_t)NN * 4;                  // N*4
    float* rg   = ahj1 + (size_t)NN * 4;                  // L*9
    float* sig  = rg + LL * 9;                            // L*192
    _Float16* bfB = (_Float16*)(sig + LL * 192);          // L*80*64 f16
    int* csroff3 = (int*)(bfB + LL * 5120);               // NK3+1
    int* bucketTotal = csroff3 + NK3 + 1;                 // NBKT
    int* blockHist   = bucketTotal + NBKT;                // NB2*HP2 (401 KB)
    unsigned* bucketed = (unsigned*)(blockHist + (size_t)NB2 * HP2);  // E
    unsigned short* csrpk = (unsigned short*)(bucketed + EE);          // E

    // pass A | layer-0 GEMM | small — independent, one launch, no atomics
    k_fusedA<<<NB2 + NBM + 1, 256, 0, stream>>>(row, et, blockHist,
                                                x, we, thj, hw0, ahj0,
                                                ef, tg, wr, rg, sig, bfB);
    k_colscan<<<NBKT, 256, 0, stream>>>(blockHist, bucketTotal);
    k_bucket<<<NB2, 256, 0, stream>>>(row, et, col, bucketTotal, blockHist,
                                      bucketed);
    k_emit3<<<NBKT, 256, 0, stream>>>(bucketed, bucketTotal, csroff3, csrpk);

    // layer-0 aggregation -> h1 f16 staged in d_out
    k_edge0<<<NN / 4, 256, 0, stream>>>(csroff3, csrpk, rg, sig, ahj0, hw0,
                                        x, h1h);
    // layer-1 GEMM: hw1 = h1@we1 (f16, [n][3][64]), ahj1
    k_mm1<<<(NK3 + 63) / 64, 256, 0, stream>>>(h1h, bfB + 5120, hw1, ahj1);
    // layer-1 aggregation -> final f32 output
    k_edge1<<<NN / 4, 256, 0, stream>>>(csroff3, csrpk, rg + 9, sig + 192,
                                        ahj1, hw1, out);
}